// Round 16
// baseline (191.849 us; speedup 1.0000x reference)
//
#include <hip/hip_runtime.h>
#include <hip/hip_bf16.h>
#include <cstdint>
#include <cstddef>

#define EMB   2048
#define NH_   32
#define NG_   8
#define DH_   64
#define SEQ_  2048
#define BB_   2
#define MTOT  4096
#define LDQKV 3072
#define SM_C  0.18033688f   // 0.125 * log2(e)

typedef __attribute__((ext_vector_type(8))) short s16x8;
typedef __attribute__((ext_vector_type(8))) unsigned short u16x8;
typedef __attribute__((ext_vector_type(4))) float f32x4;
typedef __attribute__((ext_vector_type(16))) float f32x16;
typedef __attribute__((ext_vector_type(4))) unsigned int u32x4;
typedef __attribute__((ext_vector_type(2))) unsigned int u32x2;
typedef __attribute__((ext_vector_type(2))) int i32x2;

__device__ __forceinline__ float bf2f(unsigned short u) {
  unsigned int x = (unsigned int)u << 16; return __uint_as_float(x);
}
__device__ __forceinline__ unsigned short f2bf(float f) {
  unsigned int x = __float_as_uint(f);
  x = x + 0x7FFFu + ((x >> 16) & 1u);          // RNE
  return (unsigned short)(x >> 16);
}
__device__ __forceinline__ float ninf() { return __int_as_float(0xff800000); }
__device__ __forceinline__ unsigned int pack_bf2(float a, float b) {
  unsigned int r;
  asm("v_cvt_pk_bf16_f32 %0, %1, %2" : "=v"(r) : "v"(a), "v"(b));
  return r;
}
// lane i (<32): a.lo stays, a.hi <- b.lo ; b.lo <- a.hi, b.hi stays (32-lane half swap)
__device__ __forceinline__ void plswap(unsigned int& a, unsigned int& b) {
  i32x2 r = __builtin_amdgcn_permlane32_swap((int)a, (int)b, false, false);
  a = (unsigned int)r[0]; b = (unsigned int)r[1];
}
__device__ __forceinline__ void plswapf(float& a, float& b) {
  unsigned int ua = __float_as_uint(a), ub = __float_as_uint(b);
  plswap(ua, ub);
  a = __uint_as_float(ua); b = __uint_as_float(ub);
}

__device__ __forceinline__ void glds16(const void* g, void* l) {
  __builtin_amdgcn_global_load_lds((const __attribute__((address_space(1))) void*)g,
                                   (__attribute__((address_space(3))) void*)l, 16, 0, 0);
}

// hw sincos, input radians; revolutions conversion + range reduction
__device__ __forceinline__ void hw_sincos(float ang, float& c, float& s) {
  float rev = ang * 0.15915494309f;
  rev = rev - floorf(rev);
  asm("v_cos_f32 %0, %1" : "=v"(c) : "v"(rev));
  asm("v_sin_f32 %0, %1" : "=v"(s) : "v"(rev));
}

// ---------- merged prep: x f32->bf16 (seg 0) + 4 weight transposes (segs 1..4) ----------
__global__ __launch_bounds__(256)
void prep(const float* __restrict__ x, const float* __restrict__ Wq,
          const float* __restrict__ Wk, const float* __restrict__ Wv,
          const float* __restrict__ Wo, unsigned short* __restrict__ xb,
          unsigned short* __restrict__ Wt, unsigned short* __restrict__ Wot) {
  __shared__ float tile[64][65];
  const int tid = threadIdx.x;
  const int bid = blockIdx.x;
  if (bid < 4096) {                       // cvtx
    size_t i = (size_t)bid * 256 + tid;
    float4 a = *(const float4*)(x + i * 8);
    float4 c = *(const float4*)(x + i * 8 + 4);
    u16x8 o;
    o[0] = f2bf(a.x); o[1] = f2bf(a.y); o[2] = f2bf(a.z); o[3] = f2bf(a.w);
    o[4] = f2bf(c.x); o[5] = f2bf(c.y); o[6] = f2bf(c.z); o[7] = f2bf(c.w);
    *(u16x8*)(xb + i * 8) = o;
    return;
  }
  const float* in; unsigned short* out; int N; int local;
  if (bid < 5120)      { in = Wq; out = Wt;                       N = 2048; local = bid - 4096; }
  else if (bid < 5376) { in = Wk; out = Wt + (size_t)2048 * 2048; N = 512;  local = bid - 5120; }
  else if (bid < 5632) { in = Wv; out = Wt + (size_t)2560 * 2048; N = 512;  local = bid - 5376; }
  else                 { in = Wo; out = Wot;                      N = 2048; local = bid - 5632; }
  const int ntile = N >> 6;
  const int n0 = (local % ntile) * 64, k0 = (local / ntile) * 64;
  #pragma unroll
  for (int jj = 0; jj < 4; ++jj) {
    int r = (tid >> 4) + jj * 16;
    int c = (tid & 15) * 4;
    float4 v = *(const float4*)(in + (size_t)(k0 + r) * N + n0 + c);
    tile[r][c] = v.x; tile[r][c + 1] = v.y; tile[r][c + 2] = v.z; tile[r][c + 3] = v.w;
  }
  __syncthreads();
  #pragma unroll
  for (int rep = 0; rep < 2; ++rep) {
    int u = rep * 256 + tid;
    int nl = u >> 3, ch = u & 7;
    u16x8 o;
    #pragma unroll
    for (int e = 0; e < 8; ++e) o[e] = f2bf(tile[ch * 8 + e][nl]);
    *(u16x8*)(out + (size_t)(n0 + nl) * 2048 + k0 + ch * 8) = o;
  }
}

// ---------- counted-vmcnt 256xBN GEMM: C = A[M,2048] @ Bt[N,2048]^T ----------
// Swizzle (both-sides involution): 16B-chunk ^= (row>>1)&3 -> 2-way banks (free).
template<int BN, int F32OUT>
__global__ __launch_bounds__(512, 1)
void gemm256(const unsigned short* __restrict__ A, const unsigned short* __restrict__ Bt,
             void* __restrict__ C, int ldc) {
  constexpr int NST = 2 + BN / 128;
  constexpr int BUF = 16384 + BN * 64;
  constexpr int WN = BN / 64;
  constexpr int RW = 256 / (8 / WN);
  __shared__ __align__(16) char L[4][BUF];
  const int tid = threadIdx.x;
  const int wid = tid >> 6, lane = tid & 63;
  const int wm = wid / WN, wn = wid % WN;
  const int grp = lane >> 4, l15 = lane & 15;
  const int bm = blockIdx.y * 256, bn = blockIdx.x * BN;
  const int nt = 64;

  const int srow = tid >> 2;
  const int sc = (tid & 3) ^ ((srow >> 1) & 3);  // pre-swizzled source chunk
  const int grp2 = grp ^ ((l15 >> 1) & 3);       // swizzled ds_read chunk

  auto stage_ht = [&](int t, int h) {
    const unsigned short* src = (h < 2)
      ? A  + (size_t)(bm + h * 128 + srow) * 2048 + t * 32 + sc * 8
      : Bt + (size_t)(bn + (h - 2) * 128 + srow) * 2048 + t * 32 + sc * 8;
    glds16(src, &L[t & 3][h * 8192 + wid * 1024]);
  };

  f32x4 acc[RW / 16][4] = {};

  #pragma unroll
  for (int h = 0; h < NST; ++h) stage_ht(0, h);
  #pragma unroll
  for (int h = 0; h < NST; ++h) stage_ht(1, h);
  if constexpr (BN == 256) asm volatile("s_waitcnt vmcnt(4)" ::: "memory");
  else                     asm volatile("s_waitcnt vmcnt(3)" ::: "memory");
  __builtin_amdgcn_sched_barrier(0);
  __builtin_amdgcn_s_barrier();
  __builtin_amdgcn_sched_barrier(0);

  for (int t = 0; t < nt; ++t) {
    const char* Ab = &L[t & 3][0]     + (size_t)(wm * RW + l15) * 64 + grp2 * 16;
    const char* Bb = &L[t & 3][16384] + (size_t)(wn * 64 + l15) * 64 + grp2 * 16;
    const bool pre = (t + 2 < nt);
    if (pre) { stage_ht(t + 2, 0); stage_ht(t + 2, 1); }
    s16x8 bf[4], af[4];
    #pragma unroll
    for (int j = 0; j < 4; ++j) bf[j] = *(const s16x8*)(Bb + j * 1024);
    #pragma unroll
    for (int i = 0; i < 4; ++i) af[i] = *(const s16x8*)(Ab + i * 1024);
    __builtin_amdgcn_s_setprio(1);
    #pragma unroll
    for (int i = 0; i < 4; ++i)
      #pragma unroll
      for (int j = 0; j < 4; ++j)
        acc[i][j] = __builtin_amdgcn_mfma_f32_16x16x32_bf16(af[i], bf[j], acc[i][j], 0, 0, 0);
    __builtin_amdgcn_s_setprio(0);
    if constexpr (BN == 256) {
      if (pre) { stage_ht(t + 2, 2); stage_ht(t + 2, 3); }
      #pragma unroll
      for (int i = 0; i < 4; ++i) af[i] = *(const s16x8*)(Ab + (4 + i) * 1024);
      __builtin_amdgcn_s_setprio(1);
      #pragma unroll
      for (int i = 0; i < 4; ++i)
        #pragma unroll
        for (int j = 0; j < 4; ++j)
          acc[4 + i][j] = __builtin_amdgcn_mfma_f32_16x16x32_bf16(af[i], bf[j], acc[4 + i][j], 0, 0, 0);
      __builtin_amdgcn_s_setprio(0);
    } else {
      if (pre) stage_ht(t + 2, 2);
    }
    if (t + 1 < nt) {
      if (pre) {
        if constexpr (BN == 256) asm volatile("s_waitcnt vmcnt(4)" ::: "memory");
        else                     asm volatile("s_waitcnt vmcnt(3)" ::: "memory");
      } else {
        asm volatile("s_waitcnt vmcnt(0)" ::: "memory");
      }
      __builtin_amdgcn_sched_barrier(0);
      __builtin_amdgcn_s_barrier();
      __builtin_amdgcn_sched_barrier(0);
    }
  }

  #pragma unroll
  for (int i = 0; i < RW / 16; ++i)
    #pragma unroll
    for (int j = 0; j < 4; ++j)
      #pragma unroll
      for (int r = 0; r < 4; ++r) {
        int row = bm + wm * RW + i * 16 + grp * 4 + r;
        int col = bn + wn * 64 + j * 16 + l15;
        float v = acc[i][j][r];
        if (F32OUT) ((float*)C)[(size_t)row * ldc + col] = v;
        else        ((unsigned short*)C)[(size_t)row * ldc + col] = f2bf(v);
      }
}

// ---------- K/V pre-tiling + fused K RMSNorm/RoPE ----------
__global__ __launch_bounds__(256)
void kvtile_rms(const unsigned short* __restrict__ qkv, const float* __restrict__ ksc,
                const float* __restrict__ cs, const float* __restrict__ sn,
                unsigned short* __restrict__ Kt, unsigned short* __restrict__ Vt) {
  __shared__ unsigned short Kl[32][72];
  __shared__ unsigned short Vl[32][72];
  const int tid = threadIdx.x;
  const int kt = blockIdx.x;
  const int bg = blockIdx.y;
  const int b = bg >> 3, g = bg & 7;
  {
    const int row = tid >> 3, ch = tid & 7;
    const int spos = kt * 32 + row;
    u16x8 kv = *(const u16x8*)(qkv + (size_t)(b * SEQ_ + spos) * LDQKV + 2048 + g * 64 + ch * 8);
    float v[8]; float sq = 0.f;
    #pragma unroll
    for (int e = 0; e < 8; ++e) { v[e] = bf2f(kv[e]); sq += v[e] * v[e]; }
    sq += __shfl_xor(sq, 1); sq += __shfl_xor(sq, 2); sq += __shfl_xor(sq, 4);
    const float rn = rsqrtf(sq * (1.f / 64.f) + 1e-6f);
    float xn[8];
    #pragma unroll
    for (int e = 0; e < 8; ++e) xn[e] = v[e] * rn * ksc[ch * 8 + e];
    float pn[8];
    #pragma unroll
    for (int e = 0; e < 8; ++e) pn[e] = __shfl_xor(xn[e], 4);
    const bool lo = (ch < 4);
    #pragma unroll
    for (int e = 0; e < 8; ++e) {
      int d = ch * 8 + e;
      float c = cs[spos * 64 + d], si = sn[spos * 64 + d];
      float o = lo ? (xn[e] * c - pn[e] * si) : fmaf(xn[e], c, pn[e] * si);
      Kl[row][d] = f2bf(o);
    }
    u16x8 vv = *(const u16x8*)(qkv + (size_t)(b * SEQ_ + spos) * LDQKV + 2560 + g * 64 + ch * 8);
    #pragma unroll
    for (int e = 0; e < 8; ++e) Vl[row][ch * 8 + e] = vv[e];
  }
  __syncthreads();
  {
    int c = tid >> 5, row = tid & 31;
    u16x8 o;
    #pragma unroll
    for (int e = 0; e < 8; ++e) o[e] = Kl[row][c * 8 + e];
    *(u16x8*)(Kt + (((size_t)(bg * 64 + kt)) << 11) + (c * 32 + row) * 8) = o;
  }
  {
    int c = tid >> 6, d = tid & 63;
    u16x8 o;
    #pragma unroll
    for (int e = 0; e < 8; ++e) o[e] = Vl[c * 8 + e][d];
    *(u16x8*)(Vt + (((size_t)(bg * 64 + kt)) << 11) + (c * 64 + d) * 8) = o;
  }
}

// ---------- MFMA flash attention v12: uniform-length chains via split-sum ----------
// No-max softmax => partials are pure sums, so tiles qt>=32 split at k=32:
//  chain c2<32 : [part0 of tile 32+c2 : kt 0..31]              -> partial slot
//  chain c2>=32: [part1 of tile 32+j : kt 32..32+j] -> partial; then
//                [tile 31-j complete : kt 0..31-j]  -> ctx
// All 1024 blocks run 32-33 k-tiles => uniform makespan; LDS padded to 40KB
// => exactly 4 blocks/CU, whole grid resident, flat occupancy.
__global__ __launch_bounds__(256)
void attn_mfma12(const unsigned short* __restrict__ qkv, const float* __restrict__ qsc,
                 const unsigned short* __restrict__ Ktg, const unsigned short* __restrict__ Vtg,
                 unsigned short* __restrict__ xbt, unsigned short* __restrict__ WtS,
                 float* __restrict__ lbuf, unsigned short* __restrict__ ctx) {
  __shared__ __align__(16) unsigned short LA[10 * 1024];   // 16KB used + 4KB pad
  __shared__ __align__(16) unsigned short LB[10 * 1024];
  const int tid = threadIdx.x;
  const int w = tid >> 6, lane = tid & 63;
  const int l31 = lane & 31, half = lane >> 5;
  const int bid = blockIdx.x;
  const int x8 = bid & 7, c = bid >> 3;          // XCD pin, c 0..127
  const int bg = x8 + 8 * (c & 1);
  const int c2 = c >> 1;                         // 0..63
  const int b = bg >> 3, g = bg & 7, h = g * 4 + w;

  int nseg, sqt[2], sk0[2], slen[2], smode[2], sslot[2];
  if (c2 < 32) {
    nseg = 1;
    sqt[0] = 32 + c2; sk0[0] = 0; slen[0] = 32; smode[0] = 1;
    sslot[0] = ((bg * 4 + w) * 32 + c2) * 2 + 0;
  } else {
    const int j = c2 - 32;
    nseg = 2;
    sqt[0] = 32 + j;  sk0[0] = 32; slen[0] = j + 1;  smode[0] = 1;
    sslot[0] = ((bg * 4 + w) * 32 + j) * 2 + 1;
    sqt[1] = 31 - j;  sk0[1] = 0;  slen[1] = 32 - j; smode[1] = 0; sslot[1] = 0;
  }

  const size_t tbase = ((size_t)(bg * 64)) << 11;
  const int soff = (w << 9) + lane * 8;

  for (int s = 0; s < nseg; ++s) {
    const int qt = sqt[s], k0 = sk0[s];
    const int kend = k0 + slen[s];
    const int qbase = qt * 32;

    // ---- inline Q RMSNorm + RoPE (computed sincos) + SM_C scale ----
    s16x8 qf[4];
    {
      const int spos = qbase + l31;
      float qv[4][8]; float sq = 0.f;
      #pragma unroll
      for (int s2 = 0; s2 < 4; ++s2) {
        u16x8 raw = *(const u16x8*)(qkv + (size_t)(b * SEQ_ + spos) * LDQKV + h * 64 + half * 8 + s2 * 16);
        #pragma unroll
        for (int e = 0; e < 8; ++e) { qv[s2][e] = bf2f(raw[e]); sq += qv[s2][e] * qv[s2][e]; }
      }
      sq += __shfl_xor(sq, 32);
      const float rn = rsqrtf(sq * (1.f / 64.f) + 1e-6f);
      float xn[4][8];
      #pragma unroll
      for (int s2 = 0; s2 < 4; ++s2)
        #pragma unroll
        for (int e = 0; e < 8; ++e) xn[s2][e] = qv[s2][e] * rn * qsc[s2 * 16 + half * 8 + e];
      const float fs = (float)spos;
      float qo[4][8];
      #pragma unroll
      for (int s2 = 0; s2 < 2; ++s2)
        #pragma unroll
        for (int e = 0; e < 8; ++e) {
          int d = s2 * 16 + half * 8 + e;
          float invf = exp2f((float)d * -0.4152410119f);  // 10000^(-d/32)
          float c0, s0;
          hw_sincos(fs * invf, c0, s0);
          qo[s2][e]     = (xn[s2][e] * c0 - xn[s2 + 2][e] * s0) * SM_C;
          qo[s2 + 2][e] = fmaf(xn[s2 + 2][e], c0, xn[s2][e] * s0) * SM_C;
        }
      #pragma unroll
      for (int s2 = 0; s2 < 4; ++s2) {
        u32x4 t;
        t[0] = pack_bf2(qo[s2][0], qo[s2][1]); t[1] = pack_bf2(qo[s2][2], qo[s2][3]);
        t[2] = pack_bf2(qo[s2][4], qo[s2][5]); t[3] = pack_bf2(qo[s2][6], qo[s2][7]);
        qf[s2] = __builtin_bit_cast(s16x8, t);
      }
    }

    f32x16 acc0 = {}, acc1 = {};
    float l_st = 0.f;

    auto stage = [&](unsigned short* Lb, int ktA) {
      glds16(Ktg + tbase + ((size_t)ktA << 11) + soff, (char*)Lb + (w << 10));
      glds16(Vtg + tbase + ((size_t)ktA << 11) + soff, (char*)Lb + 8192 + (w << 10));
      if (ktA + 1 < kend) {
        glds16(Ktg + tbase + ((size_t)(ktA + 1) << 11) + soff, (char*)Lb + 4096 + (w << 10));
        glds16(Vtg + tbase + ((size_t)(ktA + 1) << 11) + soff, (char*)Lb + 12288 + (w << 10));
      }
    };

    auto sub = [&](const char* Kb, const char* Vb, bool diag, float& lsum) {
      s16x8 KF0 = *(const s16x8*)(Kb + (((0 + half) << 5) + l31) * 16);
      s16x8 KF1 = *(const s16x8*)(Kb + (((2 + half) << 5) + l31) * 16);
      s16x8 KF2 = *(const s16x8*)(Kb + (((4 + half) << 5) + l31) * 16);
      s16x8 KF3 = *(const s16x8*)(Kb + (((6 + half) << 5) + l31) * 16);
      s16x8 vf00 = *(const s16x8*)(Vb + (((half) << 6) + l31) * 16);
      s16x8 vf01 = *(const s16x8*)(Vb + (((2 + half) << 6) + l31) * 16);
      s16x8 vf10 = *(const s16x8*)(Vb + (((half) << 6) + 32 + l31) * 16);
      s16x8 vf11 = *(const s16x8*)(Vb + (((2 + half) << 6) + 32 + l31) * 16);
      f32x16 st = {};
      __builtin_amdgcn_s_setprio(1);
      st = __builtin_amdgcn_mfma_f32_32x32x16_bf16(KF0, qf[0], st, 0, 0, 0);
      st = __builtin_amdgcn_mfma_f32_32x32x16_bf16(KF1, qf[1], st, 0, 0, 0);
      st = __builtin_amdgcn_mfma_f32_32x32x16_bf16(KF2, qf[2], st, 0, 0, 0);
      st = __builtin_amdgcn_mfma_f32_32x32x16_bf16(KF3, qf[3], st, 0, 0, 0);
      __builtin_amdgcn_s_setprio(0);
      if (diag) {
        #pragma unroll
        for (int r2 = 0; r2 < 16; ++r2) {
          int key = (r2 & 3) + 8 * (r2 >> 2) + 4 * half;
          if (key > l31) st[r2] = ninf();
        }
      }
      float p[16];
      #pragma unroll
      for (int r2 = 0; r2 < 16; ++r2) p[r2] = exp2f(st[r2]);
      float s8[8];
      #pragma unroll
      for (int r2 = 0; r2 < 8; ++r2) s8[r2] = p[r2] + p[r2 + 8];
      lsum += ((s8[0] + s8[1]) + (s8[2] + s8[3])) + ((s8[4] + s8[5]) + (s8[6] + s8[7]));
      unsigned int PK[8];
      #pragma unroll
      for (int j2 = 0; j2 < 8; ++j2) PK[j2] = pack_bf2(p[2 * j2], p[2 * j2 + 1]);
      plswap(PK[0], PK[2]); plswap(PK[1], PK[3]);
      plswap(PK[4], PK[6]); plswap(PK[5], PK[7]);
      u32x4 pb0u, pb1u;
      pb0u[0] = PK[0]; pb0u[1] = PK[1]; pb0u[2] = PK[2]; pb0u[3] = PK[3];
      pb1u[0] = PK[4]; pb1u[1] = PK[5]; pb1u[2] = PK[6]; pb1u[3] = PK[7];
      s16x8 pb0 = __builtin_bit_cast(s16x8, pb0u);
      s16x8 pb1 = __builtin_bit_cast(s16x8, pb1u);
      __builtin_amdgcn_s_setprio(1);
      acc0 = __builtin_amdgcn_mfma_f32_32x32x16_bf16(vf00, pb0, acc0, 0, 0, 0);
      acc1 = __builtin_amdgcn_mfma_f32_32x32x16_bf16(vf10, pb0, acc1, 0, 0, 0);
      acc0 = __builtin_amdgcn_mfma_f32_32x32x16_bf16(vf01, pb1, acc0, 0, 0, 0);
      acc1 = __builtin_amdgcn_mfma_f32_32x32x16_bf16(vf11, pb1, acc1, 0, 0, 0);
      __builtin_amdgcn_s_setprio(0);
    };

    auto pair_body = [&](const unsigned short* Lb, int kt0) {
      float lsum = 0.f;
      sub((const char*)Lb, (const char*)Lb + 8192, kt0 == qt, lsum);
      if (kt0 + 1 < kend)
        sub((const char*)Lb + 4096, (const char*)Lb + 12288, kt0 + 1 == qt, lsum);
      { float a2 = lsum, b2 = lsum; plswapf(a2, b2); lsum = a2 + b2; }
      l_st += lsum;
    };

    const int nit = (slen[s] + 1) >> 1;
    __syncthreads();                 // previous segment's reads of LA/LB done
    stage(LA, k0);
    int pi = 0;
    while (true) {
      __syncthreads();
      if (pi + 1 < nit) stage(LB, k0 + 2 * (pi + 1));
      pair_body(LA, k0 + 2 * pi);
      ++pi; if (pi >= nit) break;
      __syncthreads();
      if (pi + 1 < nit) stage(LA, k0 + 2 * (pi + 1));
      pair_body(LB, k0 + 2 * pi);
      ++pi; if (pi >= nit) break;
    }

    if (smode[s] == 0) {             // complete tile: normalized ctx write
      const float linv = 1.f / l_st;
      unsigned short* orow = ctx + (size_t)(b * SEQ_ + qbase + l31) * 2048 + h * 64;
      #pragma unroll
      for (int dt = 0; dt < 2; ++dt)
        #pragma unroll
        for (int rq = 0; rq < 4; ++rq) {
          const int rr2 = rq * 4;
          const int d0 = dt * 32 + 8 * rq + 4 * half;
          float a0 = (dt ? acc1[rr2]     : acc0[rr2])     * linv;
          float a1 = (dt ? acc1[rr2 + 1] : acc0[rr2 + 1]) * linv;
          float a2 = (dt ? acc1[rr2 + 2] : acc0[rr2 + 2]) * linv;
          float a3 = (dt ? acc1[rr2 + 3] : acc0[rr2 + 3]) * linv;
          u32x2 o; o[0] = pack_bf2(a0, a1); o[1] = pack_bf2(a2, a3);
          *(u32x2*)(orow + d0) = o;
        }
    } else {                          // split chunk: raw partial write
      const int slot = sslot[s];
      unsigned short* prow = ((slot < 3072)
        ? xbt + (size_t)slot * 2048
        : WtS + (size_t)(slot - 3072) * 2048) + l31 * 64;
      #pragma unroll
      for (int dt = 0; dt < 2; ++dt)
        #pragma unroll
        for (int rq = 0; rq < 4; ++rq) {
          const int rr2 = rq * 4;
          const int d0 = dt * 32 + 8 * rq + 4 * half;
          float a0 = (dt ? acc1[rr2]     : acc0[rr2]);
          float a1 = (dt ? acc1[rr2 + 1] : acc0[rr2 + 1]);
          float a2 = (dt ? acc1[rr2 + 2] : acc0[rr2 + 2]);
          float a3 = (dt ? acc1[rr2 + 3] : acc0[rr2 + 3]);
          u32x2 o; o[0] = pack_bf2(a0, a1); o[1] = pack_bf2(a2, a3);
          *(u32x2*)(prow + d0) = o;
        }
      if (half == 0) lbuf[slot * 32 + l31] = l_st;
    }
  }
}

// ---------- combine split partials: ctx = (A + B) / (lA + lB) ----------
__global__ __launch_bounds__(256)
void combine2(const unsigned short* __restrict__ xbt, const unsigned short* __restrict__ WtS,
              const float* __restrict__ lbuf, unsigned short* __restrict__ ctx) {
  const int ct = blockIdx.x;                 // 0..2047
  const int bg = ct >> 7, rem = ct & 127, head = rem >> 5, j = rem & 31;
  const int b = bg >> 3, g = bg & 7, h = g * 4 + head;
  const int q = threadIdx.x >> 3, d0 = (threadIdx.x & 7) * 8;
  const int s0 = ct * 2, s1 = s0 + 1;
  const unsigned short* A = ((s0 < 3072) ? xbt + (size_t)s0 * 2048
                                         : WtS + (size_t)(s0 - 3072) * 2048) + q * 64 + d0;
  const unsigned short* B = ((s1 < 3072) ? xbt + (size_t)s1 * 2048
                                         : WtS + (size_t)(s1 - 3072) * 2048) + q * 64 + d0;
  const float inv = 1.f / (lbuf[s0 * 32 + q] + lbuf[s1 * 32 + q]);
  u16x8 va = *(const u16x8*)A;
  u16x8 vb = *(const u16x8*)B;
  u16x8 o;
  #pragma unroll
  for (int e = 0; e < 8; ++e) o[e] = f2bf((bf2f(va[e]) + bf2f(vb[e])) * inv);
  *(u16x8*)(ctx + (size_t)(b * SEQ_ + (32 + j) * 32 + q) * 2048 + h * 64 + d0) = o;
}

extern "C" void kernel_launch(void* const* d_in, const int* in_sizes, int n_in,
                              void* d_out, int out_size, void* d_ws, size_t ws_size,
                              hipStream_t stream) {
  const float* x  = (const float*)d_in[0];
  const float* cs = (const float*)d_in[2];
  const float* sn = (const float*)d_in[3];
  const float* Wq = (const float*)d_in[4];
  const float* Wk = (const float*)d_in[5];
  const float* Wv = (const float*)d_in[6];
  const float* Wo = (const float*)d_in[7];
  const float* qs = (const float*)d_in[8];
  const float* ks = (const float*)d_in[9];
  float* out = (float*)d_out;

  unsigned short* xb  = (unsigned short*)d_ws;
  unsigned short* Wt  = xb  + (size_t)4096 * 2048;
  unsigned short* Wot = Wt  + (size_t)3072 * 2048;
  unsigned short* qkv = Wot + (size_t)2048 * 2048;
  unsigned short* vTb = qkv + (size_t)4096 * 3072;     // Vt tiles (4 MiB)
  unsigned short* ctx = vTb + (size_t)16 * 64 * 2048;
  unsigned short* Ktt = xb;                            // xb[0..4MiB): Kt tiles
  unsigned short* xbt = xb + (size_t)2097152;          // xb tail: partial slots 0..3071
  unsigned short* WtS = Wt;                            // Wt: partial slots 3072..4095
  float*          lbufp = (float*)(Wt + (size_t)4194304);

  prep<<<6656, 256, 0, stream>>>(x, Wq, Wk, Wv, Wo, xb, Wt, Wot);
  gemm256<256, 0><<<dim3(12, 16), 512, 0, stream>>>(xb, Wt, qkv, 3072);
  kvtile_rms<<<dim3(64, 16), 256, 0, stream>>>(qkv, ks, cs, sn, Ktt, vTb);
  attn_mfma12<<<1024, 256, 0, stream>>>(qkv, qs, Ktt, vTb, xbt, WtS, lbufp, ctx);
  combine2<<<2048, 256, 0, stream>>>(xbt, WtS, lbufp, ctx);
  gemm256<128, 1><<<dim3(16, 16), 512, 0, stream>>>(ctx, Wot, out, 2048);
}

// Round 17
// 191.654 us; speedup vs baseline: 1.0010x; 1.0010x over previous
//
#include <hip/hip_runtime.h>
#include <hip/hip_bf16.h>
#include <cstdint>
#include <cstddef>

#define EMB   2048
#define NH_   32
#define NG_   8
#define DH_   64
#define SEQ_  2048
#define BB_   2
#define MTOT  4096
#define LDQKV 3072
#define SM_C  0.18033688f   // 0.125 * log2(e)

typedef __attribute__((ext_vector_type(8))) short s16x8;
typedef __attribute__((ext_vector_type(8))) unsigned short u16x8;
typedef __attribute__((ext_vector_type(4))) float f32x4;
typedef __attribute__((ext_vector_type(16))) float f32x16;
typedef __attribute__((ext_vector_type(4))) unsigned int u32x4;
typedef __attribute__((ext_vector_type(2))) unsigned int u32x2;
typedef __attribute__((ext_vector_type(2))) int i32x2;

__device__ __forceinline__ float bf2f(unsigned short u) {
  unsigned int x = (unsigned int)u << 16; return __uint_as_float(x);
}
__device__ __forceinline__ unsigned short f2bf(float f) {
  unsigned int x = __float_as_uint(f);
  x = x + 0x7FFFu + ((x >> 16) & 1u);          // RNE
  return (unsigned short)(x >> 16);
}
__device__ __forceinline__ float ninf() { return __int_as_float(0xff800000); }
__device__ __forceinline__ unsigned int pack_bf2(float a, float b) {
  unsigned int r;
  asm("v_cvt_pk_bf16_f32 %0, %1, %2" : "=v"(r) : "v"(a), "v"(b));
  return r;
}
// lane i (<32): a.lo stays, a.hi <- b.lo ; b.lo <- a.hi, b.hi stays (32-lane half swap)
__device__ __forceinline__ void plswap(unsigned int& a, unsigned int& b) {
  i32x2 r = __builtin_amdgcn_permlane32_swap((int)a, (int)b, false, false);
  a = (unsigned int)r[0]; b = (unsigned int)r[1];
}
__device__ __forceinline__ void plswapf(float& a, float& b) {
  unsigned int ua = __float_as_uint(a), ub = __float_as_uint(b);
  plswap(ua, ub);
  a = __uint_as_float(ua); b = __uint_as_float(ub);
}

__device__ __forceinline__ void glds16(const void* g, void* l) {
  __builtin_amdgcn_global_load_lds((const __attribute__((address_space(1))) void*)g,
                                   (__attribute__((address_space(3))) void*)l, 16, 0, 0);
}

// hw sincos, input radians; revolutions conversion + range reduction
__device__ __forceinline__ void hw_sincos(float ang, float& c, float& s) {
  float rev = ang * 0.15915494309f;
  rev = rev - floorf(rev);
  asm("v_cos_f32 %0, %1" : "=v"(c) : "v"(rev));
  asm("v_sin_f32 %0, %1" : "=v"(s) : "v"(rev));
}

// ---------- merged prep: x f32->bf16 (seg 0) + 4 weight transposes (segs 1..4) ----------
__global__ __launch_bounds__(256)
void prep(const float* __restrict__ x, const float* __restrict__ Wq,
          const float* __restrict__ Wk, const float* __restrict__ Wv,
          const float* __restrict__ Wo, unsigned short* __restrict__ xb,
          unsigned short* __restrict__ Wt, unsigned short* __restrict__ Wot) {
  __shared__ float tile[64][65];
  const int tid = threadIdx.x;
  const int bid = blockIdx.x;
  if (bid < 4096) {                       // cvtx
    size_t i = (size_t)bid * 256 + tid;
    float4 a = *(const float4*)(x + i * 8);
    float4 c = *(const float4*)(x + i * 8 + 4);
    u16x8 o;
    o[0] = f2bf(a.x); o[1] = f2bf(a.y); o[2] = f2bf(a.z); o[3] = f2bf(a.w);
    o[4] = f2bf(c.x); o[5] = f2bf(c.y); o[6] = f2bf(c.z); o[7] = f2bf(c.w);
    *(u16x8*)(xb + i * 8) = o;
    return;
  }
  const float* in; unsigned short* out; int N; int local;
  if (bid < 5120)      { in = Wq; out = Wt;                       N = 2048; local = bid - 4096; }
  else if (bid < 5376) { in = Wk; out = Wt + (size_t)2048 * 2048; N = 512;  local = bid - 5120; }
  else if (bid < 5632) { in = Wv; out = Wt + (size_t)2560 * 2048; N = 512;  local = bid - 5376; }
  else                 { in = Wo; out = Wot;                      N = 2048; local = bid - 5632; }
  const int ntile = N >> 6;
  const int n0 = (local % ntile) * 64, k0 = (local / ntile) * 64;
  #pragma unroll
  for (int jj = 0; jj < 4; ++jj) {
    int r = (tid >> 4) + jj * 16;
    int c = (tid & 15) * 4;
    float4 v = *(const float4*)(in + (size_t)(k0 + r) * N + n0 + c);
    tile[r][c] = v.x; tile[r][c + 1] = v.y; tile[r][c + 2] = v.z; tile[r][c + 3] = v.w;
  }
  __syncthreads();
  #pragma unroll
  for (int rep = 0; rep < 2; ++rep) {
    int u = rep * 256 + tid;
    int nl = u >> 3, ch = u & 7;
    u16x8 o;
    #pragma unroll
    for (int e = 0; e < 8; ++e) o[e] = f2bf(tile[ch * 8 + e][nl]);
    *(u16x8*)(out + (size_t)(n0 + nl) * 2048 + k0 + ch * 8) = o;
  }
}

// ---------- counted-vmcnt 256xBN GEMM: C = A[M,2048] @ Bt[N,2048]^T ----------
// Swizzle (both-sides involution): 16B-chunk ^= (row>>1)&3 -> 2-way banks (free).
template<int BN, int F32OUT>
__global__ __launch_bounds__(512, 1)
void gemm256(const unsigned short* __restrict__ A, const unsigned short* __restrict__ Bt,
             void* __restrict__ C, int ldc) {
  constexpr int NST = 2 + BN / 128;
  constexpr int BUF = 16384 + BN * 64;
  constexpr int WN = BN / 64;
  constexpr int RW = 256 / (8 / WN);
  __shared__ __align__(16) char L[4][BUF];
  const int tid = threadIdx.x;
  const int wid = tid >> 6, lane = tid & 63;
  const int wm = wid / WN, wn = wid % WN;
  const int grp = lane >> 4, l15 = lane & 15;
  const int bm = blockIdx.y * 256, bn = blockIdx.x * BN;
  const int nt = 64;

  const int srow = tid >> 2;
  const int sc = (tid & 3) ^ ((srow >> 1) & 3);  // pre-swizzled source chunk
  const int grp2 = grp ^ ((l15 >> 1) & 3);       // swizzled ds_read chunk

  auto stage_ht = [&](int t, int h) {
    const unsigned short* src = (h < 2)
      ? A  + (size_t)(bm + h * 128 + srow) * 2048 + t * 32 + sc * 8
      : Bt + (size_t)(bn + (h - 2) * 128 + srow) * 2048 + t * 32 + sc * 8;
    glds16(src, &L[t & 3][h * 8192 + wid * 1024]);
  };

  f32x4 acc[RW / 16][4] = {};

  #pragma unroll
  for (int h = 0; h < NST; ++h) stage_ht(0, h);
  #pragma unroll
  for (int h = 0; h < NST; ++h) stage_ht(1, h);
  if constexpr (BN == 256) asm volatile("s_waitcnt vmcnt(4)" ::: "memory");
  else                     asm volatile("s_waitcnt vmcnt(3)" ::: "memory");
  __builtin_amdgcn_sched_barrier(0);
  __builtin_amdgcn_s_barrier();
  __builtin_amdgcn_sched_barrier(0);

  for (int t = 0; t < nt; ++t) {
    const char* Ab = &L[t & 3][0]     + (size_t)(wm * RW + l15) * 64 + grp2 * 16;
    const char* Bb = &L[t & 3][16384] + (size_t)(wn * 64 + l15) * 64 + grp2 * 16;
    const bool pre = (t + 2 < nt);
    if (pre) { stage_ht(t + 2, 0); stage_ht(t + 2, 1); }
    s16x8 bf[4], af[4];
    #pragma unroll
    for (int j = 0; j < 4; ++j) bf[j] = *(const s16x8*)(Bb + j * 1024);
    #pragma unroll
    for (int i = 0; i < 4; ++i) af[i] = *(const s16x8*)(Ab + i * 1024);
    __builtin_amdgcn_s_setprio(1);
    #pragma unroll
    for (int i = 0; i < 4; ++i)
      #pragma unroll
      for (int j = 0; j < 4; ++j)
        acc[i][j] = __builtin_amdgcn_mfma_f32_16x16x32_bf16(af[i], bf[j], acc[i][j], 0, 0, 0);
    __builtin_amdgcn_s_setprio(0);
    if constexpr (BN == 256) {
      if (pre) { stage_ht(t + 2, 2); stage_ht(t + 2, 3); }
      #pragma unroll
      for (int i = 0; i < 4; ++i) af[i] = *(const s16x8*)(Ab + (4 + i) * 1024);
      __builtin_amdgcn_s_setprio(1);
      #pragma unroll
      for (int i = 0; i < 4; ++i)
        #pragma unroll
        for (int j = 0; j < 4; ++j)
          acc[4 + i][j] = __builtin_amdgcn_mfma_f32_16x16x32_bf16(af[i], bf[j], acc[4 + i][j], 0, 0, 0);
      __builtin_amdgcn_s_setprio(0);
    } else {
      if (pre) stage_ht(t + 2, 2);
    }
    if (t + 1 < nt) {
      if (pre) {
        if constexpr (BN == 256) asm volatile("s_waitcnt vmcnt(4)" ::: "memory");
        else                     asm volatile("s_waitcnt vmcnt(3)" ::: "memory");
      } else {
        asm volatile("s_waitcnt vmcnt(0)" ::: "memory");
      }
      __builtin_amdgcn_sched_barrier(0);
      __builtin_amdgcn_s_barrier();
      __builtin_amdgcn_sched_barrier(0);
    }
  }

  #pragma unroll
  for (int i = 0; i < RW / 16; ++i)
    #pragma unroll
    for (int j = 0; j < 4; ++j)
      #pragma unroll
      for (int r = 0; r < 4; ++r) {
        int row = bm + wm * RW + i * 16 + grp * 4 + r;
        int col = bn + wn * 64 + j * 16 + l15;
        float v = acc[i][j][r];
        if (F32OUT) ((float*)C)[(size_t)row * ldc + col] = v;
        else        ((unsigned short*)C)[(size_t)row * ldc + col] = f2bf(v);
      }
}

// ---------- K/V pre-tiling + fused K RMSNorm/RoPE ----------
__global__ __launch_bounds__(256)
void kvtile_rms(const unsigned short* __restrict__ qkv, const float* __restrict__ ksc,
                const float* __restrict__ cs, const float* __restrict__ sn,
                unsigned short* __restrict__ Kt, unsigned short* __restrict__ Vt) {
  __shared__ unsigned short Kl[32][72];
  __shared__ unsigned short Vl[32][72];
  const int tid = threadIdx.x;
  const int kt = blockIdx.x;
  const int bg = blockIdx.y;
  const int b = bg >> 3, g = bg & 7;
  {
    const int row = tid >> 3, ch = tid & 7;
    const int spos = kt * 32 + row;
    u16x8 kv = *(const u16x8*)(qkv + (size_t)(b * SEQ_ + spos) * LDQKV + 2048 + g * 64 + ch * 8);
    float v[8]; float sq = 0.f;
    #pragma unroll
    for (int e = 0; e < 8; ++e) { v[e] = bf2f(kv[e]); sq += v[e] * v[e]; }
    sq += __shfl_xor(sq, 1); sq += __shfl_xor(sq, 2); sq += __shfl_xor(sq, 4);
    const float rn = rsqrtf(sq * (1.f / 64.f) + 1e-6f);
    float xn[8];
    #pragma unroll
    for (int e = 0; e < 8; ++e) xn[e] = v[e] * rn * ksc[ch * 8 + e];
    float pn[8];
    #pragma unroll
    for (int e = 0; e < 8; ++e) pn[e] = __shfl_xor(xn[e], 4);
    const bool lo = (ch < 4);
    #pragma unroll
    for (int e = 0; e < 8; ++e) {
      int d = ch * 8 + e;
      float c = cs[spos * 64 + d], si = sn[spos * 64 + d];
      float o = lo ? (xn[e] * c - pn[e] * si) : fmaf(xn[e], c, pn[e] * si);
      Kl[row][d] = f2bf(o);
    }
    u16x8 vv = *(const u16x8*)(qkv + (size_t)(b * SEQ_ + spos) * LDQKV + 2560 + g * 64 + ch * 8);
    #pragma unroll
    for (int e = 0; e < 8; ++e) Vl[row][ch * 8 + e] = vv[e];
  }
  __syncthreads();
  {
    int c = tid >> 5, row = tid & 31;
    u16x8 o;
    #pragma unroll
    for (int e = 0; e < 8; ++e) o[e] = Kl[row][c * 8 + e];
    *(u16x8*)(Kt + (((size_t)(bg * 64 + kt)) << 11) + (c * 32 + row) * 8) = o;
  }
  {
    int c = tid >> 6, d = tid & 63;
    u16x8 o;
    #pragma unroll
    for (int e = 0; e < 8; ++e) o[e] = Vl[c * 8 + e][d];
    *(u16x8*)(Vt + (((size_t)(bg * 64 + kt)) << 11) + (c * 64 + d) * 8) = o;
  }
}

// ---------- MFMA flash attention v13: uniform chains, 32KB LDS (pad removed) ----------
// v12 structure (split-sum uniform 32-33 kt blocks) with LA/LB back to 16KB
// each: LDS_Block_Size 32768 -> >=4 blocks/CU resident (the 40KB pad of v12
// silently halved residency; 32KB already guarantees grid-limited 4/CU).
__global__ __launch_bounds__(256)
void attn_mfma13(const unsigned short* __restrict__ qkv, const float* __restrict__ qsc,
                 const unsigned short* __restrict__ Ktg, const unsigned short* __restrict__ Vtg,
                 unsigned short* __restrict__ xbt, unsigned short* __restrict__ WtS,
                 float* __restrict__ lbuf, unsigned short* __restrict__ ctx) {
  __shared__ __align__(16) unsigned short LA[8 * 1024];
  __shared__ __align__(16) unsigned short LB[8 * 1024];
  const int tid = threadIdx.x;
  const int w = tid >> 6, lane = tid & 63;
  const int l31 = lane & 31, half = lane >> 5;
  const int bid = blockIdx.x;
  const int x8 = bid & 7, c = bid >> 3;          // XCD pin, c 0..127
  const int bg = x8 + 8 * (c & 1);
  const int c2 = c >> 1;                         // 0..63
  const int b = bg >> 3, g = bg & 7, h = g * 4 + w;

  int nseg, sqt[2], sk0[2], slen[2], smode[2], sslot[2];
  if (c2 < 32) {
    nseg = 1;
    sqt[0] = 32 + c2; sk0[0] = 0; slen[0] = 32; smode[0] = 1;
    sslot[0] = ((bg * 4 + w) * 32 + c2) * 2 + 0;
  } else {
    const int j = c2 - 32;
    nseg = 2;
    sqt[0] = 32 + j;  sk0[0] = 32; slen[0] = j + 1;  smode[0] = 1;
    sslot[0] = ((bg * 4 + w) * 32 + j) * 2 + 1;
    sqt[1] = 31 - j;  sk0[1] = 0;  slen[1] = 32 - j; smode[1] = 0; sslot[1] = 0;
  }

  const size_t tbase = ((size_t)(bg * 64)) << 11;
  const int soff = (w << 9) + lane * 8;

  for (int s = 0; s < nseg; ++s) {
    const int qt = sqt[s], k0 = sk0[s];
    const int kend = k0 + slen[s];
    const int qbase = qt * 32;

    // ---- inline Q RMSNorm + RoPE (computed sincos) + SM_C scale ----
    s16x8 qf[4];
    {
      const int spos = qbase + l31;
      float qv[4][8]; float sq = 0.f;
      #pragma unroll
      for (int s2 = 0; s2 < 4; ++s2) {
        u16x8 raw = *(const u16x8*)(qkv + (size_t)(b * SEQ_ + spos) * LDQKV + h * 64 + half * 8 + s2 * 16);
        #pragma unroll
        for (int e = 0; e < 8; ++e) { qv[s2][e] = bf2f(raw[e]); sq += qv[s2][e] * qv[s2][e]; }
      }
      sq += __shfl_xor(sq, 32);
      const float rn = rsqrtf(sq * (1.f / 64.f) + 1e-6f);
      float xn[4][8];
      #pragma unroll
      for (int s2 = 0; s2 < 4; ++s2)
        #pragma unroll
        for (int e = 0; e < 8; ++e) xn[s2][e] = qv[s2][e] * rn * qsc[s2 * 16 + half * 8 + e];
      const float fs = (float)spos;
      float qo[4][8];
      #pragma unroll
      for (int s2 = 0; s2 < 2; ++s2)
        #pragma unroll
        for (int e = 0; e < 8; ++e) {
          int d = s2 * 16 + half * 8 + e;
          float invf = exp2f((float)d * -0.4152410119f);  // 10000^(-d/32)
          float c0, s0;
          hw_sincos(fs * invf, c0, s0);
          qo[s2][e]     = (xn[s2][e] * c0 - xn[s2 + 2][e] * s0) * SM_C;
          qo[s2 + 2][e] = fmaf(xn[s2 + 2][e], c0, xn[s2][e] * s0) * SM_C;
        }
      #pragma unroll
      for (int s2 = 0; s2 < 4; ++s2) {
        u32x4 t;
        t[0] = pack_bf2(qo[s2][0], qo[s2][1]); t[1] = pack_bf2(qo[s2][2], qo[s2][3]);
        t[2] = pack_bf2(qo[s2][4], qo[s2][5]); t[3] = pack_bf2(qo[s2][6], qo[s2][7]);
        qf[s2] = __builtin_bit_cast(s16x8, t);
      }
    }

    f32x16 acc0 = {}, acc1 = {};
    float l_st = 0.f;

    auto stage = [&](unsigned short* Lb, int ktA) {
      glds16(Ktg + tbase + ((size_t)ktA << 11) + soff, (char*)Lb + (w << 10));
      glds16(Vtg + tbase + ((size_t)ktA << 11) + soff, (char*)Lb + 8192 + (w << 10));
      if (ktA + 1 < kend) {
        glds16(Ktg + tbase + ((size_t)(ktA + 1) << 11) + soff, (char*)Lb + 4096 + (w << 10));
        glds16(Vtg + tbase + ((size_t)(ktA + 1) << 11) + soff, (char*)Lb + 12288 + (w << 10));
      }
    };

    auto sub = [&](const char* Kb, const char* Vb, bool diag, float& lsum) {
      s16x8 KF0 = *(const s16x8*)(Kb + (((0 + half) << 5) + l31) * 16);
      s16x8 KF1 = *(const s16x8*)(Kb + (((2 + half) << 5) + l31) * 16);
      s16x8 KF2 = *(const s16x8*)(Kb + (((4 + half) << 5) + l31) * 16);
      s16x8 KF3 = *(const s16x8*)(Kb + (((6 + half) << 5) + l31) * 16);
      s16x8 vf00 = *(const s16x8*)(Vb + (((half) << 6) + l31) * 16);
      s16x8 vf01 = *(const s16x8*)(Vb + (((2 + half) << 6) + l31) * 16);
      s16x8 vf10 = *(const s16x8*)(Vb + (((half) << 6) + 32 + l31) * 16);
      s16x8 vf11 = *(const s16x8*)(Vb + (((2 + half) << 6) + 32 + l31) * 16);
      f32x16 st = {};
      __builtin_amdgcn_s_setprio(1);
      st = __builtin_amdgcn_mfma_f32_32x32x16_bf16(KF0, qf[0], st, 0, 0, 0);
      st = __builtin_amdgcn_mfma_f32_32x32x16_bf16(KF1, qf[1], st, 0, 0, 0);
      st = __builtin_amdgcn_mfma_f32_32x32x16_bf16(KF2, qf[2], st, 0, 0, 0);
      st = __builtin_amdgcn_mfma_f32_32x32x16_bf16(KF3, qf[3], st, 0, 0, 0);
      __builtin_amdgcn_s_setprio(0);
      if (diag) {
        #pragma unroll
        for (int r2 = 0; r2 < 16; ++r2) {
          int key = (r2 & 3) + 8 * (r2 >> 2) + 4 * half;
          if (key > l31) st[r2] = ninf();
        }
      }
      float p[16];
      #pragma unroll
      for (int r2 = 0; r2 < 16; ++r2) p[r2] = exp2f(st[r2]);
      float s8[8];
      #pragma unroll
      for (int r2 = 0; r2 < 8; ++r2) s8[r2] = p[r2] + p[r2 + 8];
      lsum += ((s8[0] + s8[1]) + (s8[2] + s8[3])) + ((s8[4] + s8[5]) + (s8[6] + s8[7]));
      unsigned int PK[8];
      #pragma unroll
      for (int j2 = 0; j2 < 8; ++j2) PK[j2] = pack_bf2(p[2 * j2], p[2 * j2 + 1]);
      plswap(PK[0], PK[2]); plswap(PK[1], PK[3]);
      plswap(PK[4], PK[6]); plswap(PK[5], PK[7]);
      u32x4 pb0u, pb1u;
      pb0u[0] = PK[0]; pb0u[1] = PK[1]; pb0u[2] = PK[2]; pb0u[3] = PK[3];
      pb1u[0] = PK[4]; pb1u[1] = PK[5]; pb1u[2] = PK[6]; pb1u[3] = PK[7];
      s16x8 pb0 = __builtin_bit_cast(s16x8, pb0u);
      s16x8 pb1 = __builtin_bit_cast(s16x8, pb1u);
      __builtin_amdgcn_s_setprio(1);
      acc0 = __builtin_amdgcn_mfma_f32_32x32x16_bf16(vf00, pb0, acc0, 0, 0, 0);
      acc1 = __builtin_amdgcn_mfma_f32_32x32x16_bf16(vf10, pb0, acc1, 0, 0, 0);
      acc0 = __builtin_amdgcn_mfma_f32_32x32x16_bf16(vf01, pb1, acc0, 0, 0, 0);
      acc1 = __builtin_amdgcn_mfma_f32_32x32x16_bf16(vf11, pb1, acc1, 0, 0, 0);
      __builtin_amdgcn_s_setprio(0);
    };

    auto pair_body = [&](const unsigned short* Lb, int kt0) {
      float lsum = 0.f;
      sub((const char*)Lb, (const char*)Lb + 8192, kt0 == qt, lsum);
      if (kt0 + 1 < kend)
        sub((const char*)Lb + 4096, (const char*)Lb + 12288, kt0 + 1 == qt, lsum);
      { float a2 = lsum, b2 = lsum; plswapf(a2, b2); lsum = a2 + b2; }
      l_st += lsum;
    };

    const int nit = (slen[s] + 1) >> 1;
    __syncthreads();                 // previous segment's reads of LA/LB done
    stage(LA, k0);
    int pi = 0;
    while (true) {
      __syncthreads();
      if (pi + 1 < nit) stage(LB, k0 + 2 * (pi + 1));
      pair_body(LA, k0 + 2 * pi);
      ++pi; if (pi >= nit) break;
      __syncthreads();
      if (pi + 1 < nit) stage(LA, k0 + 2 * (pi + 1));
      pair_body(LB, k0 + 2 * pi);
      ++pi; if (pi >= nit) break;
    }

    if (smode[s] == 0) {             // complete tile: normalized ctx write
      const float linv = 1.f / l_st;
      unsigned short* orow = ctx + (size_t)(b * SEQ_ + qbase + l31) * 2048 + h * 64;
      #pragma unroll
      for (int dt = 0; dt < 2; ++dt)
        #pragma unroll
        for (int rq = 0; rq < 4; ++rq) {
          const int rr2 = rq * 4;
          const int d0 = dt * 32 + 8 * rq + 4 * half;
          float a0 = (dt ? acc1[rr2]     : acc0[rr2])     * linv;
          float a1 = (dt ? acc1[rr2 + 1] : acc0[rr2 + 1]) * linv;
          float a2 = (dt ? acc1[rr2 + 2] : acc0[rr2 + 2]) * linv;
          float a3 = (dt ? acc1[rr2 + 3] : acc0[rr2 + 3]) * linv;
          u32x2 o; o[0] = pack_bf2(a0, a1); o[1] = pack_bf2(a2, a3);
          *(u32x2*)(orow + d0) = o;
        }
    } else {                          // split chunk: raw partial write
      const int slot = sslot[s];
      unsigned short* prow = ((slot < 3072)
        ? xbt + (size_t)slot * 2048
        : WtS + (size_t)(slot - 3072) * 2048) + l31 * 64;
      #pragma unroll
      for (int dt = 0; dt < 2; ++dt)
        #pragma unroll
        for (int rq = 0; rq < 4; ++rq) {
          const int rr2 = rq * 4;
          const int d0 = dt * 32 + 8 * rq + 4 * half;
          float a0 = (dt ? acc1[rr2]     : acc0[rr2]);
          float a1 = (dt ? acc1[rr2 + 1] : acc0[rr2 + 1]);
          float a2 = (dt ? acc1[rr2 + 2] : acc0[rr2 + 2]);
          float a3 = (dt ? acc1[rr2 + 3] : acc0[rr2 + 3]);
          u32x2 o; o[0] = pack_bf2(a0, a1); o[1] = pack_bf2(a2, a3);
          *(u32x2*)(prow + d0) = o;
        }
      if (half == 0) lbuf[slot * 32 + l31] = l_st;
    }
  }
}

// ---------- combine split partials: ctx = (A + B) / (lA + lB) ----------
__global__ __launch_bounds__(256)
void combine2(const unsigned short* __restrict__ xbt, const unsigned short* __restrict__ WtS,
              const float* __restrict__ lbuf, unsigned short* __restrict__ ctx) {
  const int ct = blockIdx.x;                 // 0..2047
  const int bg = ct >> 7, rem = ct & 127, head = rem >> 5, j = rem & 31;
  const int b = bg >> 3, g = bg & 7, h = g * 4 + head;
  const int q = threadIdx.x >> 3, d0 = (threadIdx.x & 7) * 8;
  const int s0 = ct * 2, s1 = s0 + 1;
  const unsigned short* A = ((s0 < 3072) ? xbt + (size_t)s0 * 2048
                                         : WtS + (size_t)(s0 - 3072) * 2048) + q * 64 + d0;
  const unsigned short* B = ((s1 < 3072) ? xbt + (size_t)s1 * 2048
                                         : WtS + (size_t)(s1 - 3072) * 2048) + q * 64 + d0;
  const float inv = 1.f / (lbuf[s0 * 32 + q] + lbuf[s1 * 32 + q]);
  u16x8 va = *(const u16x8*)A;
  u16x8 vb = *(const u16x8*)B;
  u16x8 o;
  #pragma unroll
  for (int e = 0; e < 8; ++e) o[e] = f2bf((bf2f(va[e]) + bf2f(vb[e])) * inv);
  *(u16x8*)(ctx + (size_t)(b * SEQ_ + (32 + j) * 32 + q) * 2048 + h * 64 + d0) = o;
}

extern "C" void kernel_launch(void* const* d_in, const int* in_sizes, int n_in,
                              void* d_out, int out_size, void* d_ws, size_t ws_size,
                              hipStream_t stream) {
  const float* x  = (const float*)d_in[0];
  const float* cs = (const float*)d_in[2];
  const float* sn = (const float*)d_in[3];
  const float* Wq = (const float*)d_in[4];
  const float* Wk = (const float*)d_in[5];
  const float* Wv = (const float*)d_in[6];
  const float* Wo = (const float*)d_in[7];
  const float* qs = (const float*)d_in[8];
  const float* ks = (const float*)d_in[9];
  float* out = (float*)d_out;

  unsigned short* xb  = (unsigned short*)d_ws;
  unsigned short* Wt  = xb  + (size_t)4096 * 2048;
  unsigned short* Wot = Wt  + (size_t)3072 * 2048;
  unsigned short* qkv = Wot + (size_t)2048 * 2048;
  unsigned short* vTb = qkv + (size_t)4096 * 3072;     // Vt tiles (4 MiB)
  unsigned short* ctx = vTb + (size_t)16 * 64 * 2048;
  unsigned short* Ktt = xb;                            // xb[0..4MiB): Kt tiles
  unsigned short* xbt = xb + (size_t)2097152;          // xb tail: partial slots 0..3071
  unsigned short* WtS = Wt;                            // Wt: partial slots 3072..4095
  float*          lbufp = (float*)(Wt + (size_t)4194304);

  prep<<<6656, 256, 0, stream>>>(x, Wq, Wk, Wv, Wo, xb, Wt, Wot);
  gemm256<256, 0><<<dim3(12, 16), 512, 0, stream>>>(xb, Wt, qkv, 3072);
  kvtile_rms<<<dim3(64, 16), 256, 0, stream>>>(qkv, ks, cs, sn, Ktt, vTb);
  attn_mfma13<<<1024, 256, 0, stream>>>(qkv, qs, Ktt, vTb, xbt, WtS, lbufp, ctx);
  combine2<<<2048, 256, 0, stream>>>(xbt, WtS, lbufp, ctx);
  gemm256<128, 1><<<dim3(16, 16), 512, 0, stream>>>(ctx, Wot, out, 2048);
}

// Round 18
// 186.592 us; speedup vs baseline: 1.0282x; 1.0271x over previous
//
#include <hip/hip_runtime.h>
#include <hip/hip_bf16.h>
#include <cstdint>
#include <cstddef>

#define EMB   2048
#define NH_   32
#define NG_   8
#define DH_   64
#define SEQ_  2048
#define BB_   2
#define MTOT  4096
#define LDQKV 3072
#define SM_C  0.18033688f   // 0.125 * log2(e)

typedef __attribute__((ext_vector_type(8))) short s16x8;
typedef __attribute__((ext_vector_type(8))) unsigned short u16x8;
typedef __attribute__((ext_vector_type(4))) float f32x4;
typedef __attribute__((ext_vector_type(16))) float f32x16;
typedef __attribute__((ext_vector_type(4))) unsigned int u32x4;
typedef __attribute__((ext_vector_type(2))) unsigned int u32x2;
typedef __attribute__((ext_vector_type(2))) int i32x2;

__device__ __forceinline__ float bf2f(unsigned short u) {
  unsigned int x = (unsigned int)u << 16; return __uint_as_float(x);
}
__device__ __forceinline__ unsigned short f2bf(float f) {
  unsigned int x = __float_as_uint(f);
  x = x + 0x7FFFu + ((x >> 16) & 1u);          // RNE
  return (unsigned short)(x >> 16);
}
__device__ __forceinline__ float ninf() { return __int_as_float(0xff800000); }
__device__ __forceinline__ unsigned int pack_bf2(float a, float b) {
  unsigned int r;
  asm("v_cvt_pk_bf16_f32 %0, %1, %2" : "=v"(r) : "v"(a), "v"(b));
  return r;
}
// lane i (<32): a.lo stays, a.hi <- b.lo ; b.lo <- a.hi, b.hi stays (32-lane half swap)
__device__ __forceinline__ void plswap(unsigned int& a, unsigned int& b) {
  i32x2 r = __builtin_amdgcn_permlane32_swap((int)a, (int)b, false, false);
  a = (unsigned int)r[0]; b = (unsigned int)r[1];
}
__device__ __forceinline__ void plswapf(float& a, float& b) {
  unsigned int ua = __float_as_uint(a), ub = __float_as_uint(b);
  plswap(ua, ub);
  a = __uint_as_float(ua); b = __uint_as_float(ub);
}

__device__ __forceinline__ void glds16(const void* g, void* l) {
  __builtin_amdgcn_global_load_lds((const __attribute__((address_space(1))) void*)g,
                                   (__attribute__((address_space(3))) void*)l, 16, 0, 0);
}

// hw sincos, input radians; revolutions conversion + range reduction
__device__ __forceinline__ void hw_sincos(float ang, float& c, float& s) {
  float rev = ang * 0.15915494309f;
  rev = rev - floorf(rev);
  asm("v_cos_f32 %0, %1" : "=v"(c) : "v"(rev));
  asm("v_sin_f32 %0, %1" : "=v"(s) : "v"(rev));
}

// ---------- merged prep: x f32->bf16 (seg 0) + 4 weight transposes (segs 1..4) ----------
__global__ __launch_bounds__(256)
void prep(const float* __restrict__ x, const float* __restrict__ Wq,
          const float* __restrict__ Wk, const float* __restrict__ Wv,
          const float* __restrict__ Wo, unsigned short* __restrict__ xb,
          unsigned short* __restrict__ Wt, unsigned short* __restrict__ Wot) {
  __shared__ float tile[64][65];
  const int tid = threadIdx.x;
  const int bid = blockIdx.x;
  if (bid < 4096) {                       // cvtx
    size_t i = (size_t)bid * 256 + tid;
    float4 a = *(const float4*)(x + i * 8);
    float4 c = *(const float4*)(x + i * 8 + 4);
    u16x8 o;
    o[0] = f2bf(a.x); o[1] = f2bf(a.y); o[2] = f2bf(a.z); o[3] = f2bf(a.w);
    o[4] = f2bf(c.x); o[5] = f2bf(c.y); o[6] = f2bf(c.z); o[7] = f2bf(c.w);
    *(u16x8*)(xb + i * 8) = o;
    return;
  }
  const float* in; unsigned short* out; int N; int local;
  if (bid < 5120)      { in = Wq; out = Wt;                       N = 2048; local = bid - 4096; }
  else if (bid < 5376) { in = Wk; out = Wt + (size_t)2048 * 2048; N = 512;  local = bid - 5120; }
  else if (bid < 5632) { in = Wv; out = Wt + (size_t)2560 * 2048; N = 512;  local = bid - 5376; }
  else                 { in = Wo; out = Wot;                      N = 2048; local = bid - 5632; }
  const int ntile = N >> 6;
  const int n0 = (local % ntile) * 64, k0 = (local / ntile) * 64;
  #pragma unroll
  for (int jj = 0; jj < 4; ++jj) {
    int r = (tid >> 4) + jj * 16;
    int c = (tid & 15) * 4;
    float4 v = *(const float4*)(in + (size_t)(k0 + r) * N + n0 + c);
    tile[r][c] = v.x; tile[r][c + 1] = v.y; tile[r][c + 2] = v.z; tile[r][c + 3] = v.w;
  }
  __syncthreads();
  #pragma unroll
  for (int rep = 0; rep < 2; ++rep) {
    int u = rep * 256 + tid;
    int nl = u >> 3, ch = u & 7;
    u16x8 o;
    #pragma unroll
    for (int e = 0; e < 8; ++e) o[e] = f2bf(tile[ch * 8 + e][nl]);
    *(u16x8*)(out + (size_t)(n0 + nl) * 2048 + k0 + ch * 8) = o;
  }
}

// ---------- counted-vmcnt 256xBN GEMM: C = A[M,2048] @ Bt[N,2048]^T ----------
// Swizzle (both-sides involution): 16B-chunk ^= (row>>1)&3 -> 2-way banks (free).
template<int BN, int F32OUT>
__global__ __launch_bounds__(512, 1)
void gemm256(const unsigned short* __restrict__ A, const unsigned short* __restrict__ Bt,
             void* __restrict__ C, int ldc) {
  constexpr int BUF = 16384 + BN * 64;
  constexpr int WN = BN / 64;
  constexpr int RW = 256 / (8 / WN);
  __shared__ __align__(16) char L[4][BUF];
  const int tid = threadIdx.x;
  const int wid = tid >> 6, lane = tid & 63;
  const int wm = wid / WN, wn = wid % WN;
  const int grp = lane >> 4, l15 = lane & 15;
  const int bm = blockIdx.y * 256, bn = blockIdx.x * BN;
  const int nt = 64;

  const int srow = tid >> 2;
  const int sc = (tid & 3) ^ ((srow >> 1) & 3);  // pre-swizzled source chunk
  const int grp2 = grp ^ ((l15 >> 1) & 3);       // swizzled ds_read chunk

  auto stage_ht = [&](int t, int h) {
    const unsigned short* src = (h < 2)
      ? A  + (size_t)(bm + h * 128 + srow) * 2048 + t * 32 + sc * 8
      : Bt + (size_t)(bn + (h - 2) * 128 + srow) * 2048 + t * 32 + sc * 8;
    glds16(src, &L[t & 3][h * 8192 + wid * 1024]);
  };

  constexpr int NST = 2 + BN / 128;
  f32x4 acc[RW / 16][4] = {};

  #pragma unroll
  for (int h = 0; h < NST; ++h) stage_ht(0, h);
  #pragma unroll
  for (int h = 0; h < NST; ++h) stage_ht(1, h);
  if constexpr (BN == 256) asm volatile("s_waitcnt vmcnt(4)" ::: "memory");
  else                     asm volatile("s_waitcnt vmcnt(3)" ::: "memory");
  __builtin_amdgcn_sched_barrier(0);
  __builtin_amdgcn_s_barrier();
  __builtin_amdgcn_sched_barrier(0);

  for (int t = 0; t < nt; ++t) {
    const char* Ab = &L[t & 3][0]     + (size_t)(wm * RW + l15) * 64 + grp2 * 16;
    const char* Bb = &L[t & 3][16384] + (size_t)(wn * 64 + l15) * 64 + grp2 * 16;
    const bool pre = (t + 2 < nt);
    if (pre) { stage_ht(t + 2, 0); stage_ht(t + 2, 1); }
    s16x8 bf[4], af[4];
    #pragma unroll
    for (int j = 0; j < 4; ++j) bf[j] = *(const s16x8*)(Bb + j * 1024);
    #pragma unroll
    for (int i = 0; i < 4; ++i) af[i] = *(const s16x8*)(Ab + i * 1024);
    __builtin_amdgcn_s_setprio(1);
    #pragma unroll
    for (int i = 0; i < 4; ++i)
      #pragma unroll
      for (int j = 0; j < 4; ++j)
        acc[i][j] = __builtin_amdgcn_mfma_f32_16x16x32_bf16(af[i], bf[j], acc[i][j], 0, 0, 0);
    __builtin_amdgcn_s_setprio(0);
    if constexpr (BN == 256) {
      if (pre) { stage_ht(t + 2, 2); stage_ht(t + 2, 3); }
      #pragma unroll
      for (int i = 0; i < 4; ++i) af[i] = *(const s16x8*)(Ab + (4 + i) * 1024);
      __builtin_amdgcn_s_setprio(1);
      #pragma unroll
      for (int i = 0; i < 4; ++i)
        #pragma unroll
        for (int j = 0; j < 4; ++j)
          acc[4 + i][j] = __builtin_amdgcn_mfma_f32_16x16x32_bf16(af[i], bf[j], acc[4 + i][j], 0, 0, 0);
      __builtin_amdgcn_s_setprio(0);
    } else {
      if (pre) stage_ht(t + 2, 2);
    }
    if (t + 1 < nt) {
      if (pre) {
        if constexpr (BN == 256) asm volatile("s_waitcnt vmcnt(4)" ::: "memory");
        else                     asm volatile("s_waitcnt vmcnt(3)" ::: "memory");
      } else {
        asm volatile("s_waitcnt vmcnt(0)" ::: "memory");
      }
      __builtin_amdgcn_sched_barrier(0);
      __builtin_amdgcn_s_barrier();
      __builtin_amdgcn_sched_barrier(0);
    }
  }

  #pragma unroll
  for (int i = 0; i < RW / 16; ++i)
    #pragma unroll
    for (int j = 0; j < 4; ++j)
      #pragma unroll
      for (int r = 0; r < 4; ++r) {
        int row = bm + wm * RW + i * 16 + grp * 4 + r;
        int col = bn + wn * 64 + j * 16 + l15;
        float v = acc[i][j][r];
        if (F32OUT) ((float*)C)[(size_t)row * ldc + col] = v;
        else        ((unsigned short*)C)[(size_t)row * ldc + col] = f2bf(v);
      }
}

// ---------- K/V pre-tiling + fused K RMSNorm/RoPE ----------
__global__ __launch_bounds__(256)
void kvtile_rms(const unsigned short* __restrict__ qkv, const float* __restrict__ ksc,
                const float* __restrict__ cs, const float* __restrict__ sn,
                unsigned short* __restrict__ Kt, unsigned short* __restrict__ Vt) {
  __shared__ unsigned short Kl[32][72];
  __shared__ unsigned short Vl[32][72];
  const int tid = threadIdx.x;
  const int kt = blockIdx.x;
  const int bg = blockIdx.y;
  const int b = bg >> 3, g = bg & 7;
  {
    const int row = tid >> 3, ch = tid & 7;
    const int spos = kt * 32 + row;
    u16x8 kv = *(const u16x8*)(qkv + (size_t)(b * SEQ_ + spos) * LDQKV + 2048 + g * 64 + ch * 8);
    float v[8]; float sq = 0.f;
    #pragma unroll
    for (int e = 0; e < 8; ++e) { v[e] = bf2f(kv[e]); sq += v[e] * v[e]; }
    sq += __shfl_xor(sq, 1); sq += __shfl_xor(sq, 2); sq += __shfl_xor(sq, 4);
    const float rn = rsqrtf(sq * (1.f / 64.f) + 1e-6f);
    float xn[8];
    #pragma unroll
    for (int e = 0; e < 8; ++e) xn[e] = v[e] * rn * ksc[ch * 8 + e];
    float pn[8];
    #pragma unroll
    for (int e = 0; e < 8; ++e) pn[e] = __shfl_xor(xn[e], 4);
    const bool lo = (ch < 4);
    #pragma unroll
    for (int e = 0; e < 8; ++e) {
      int d = ch * 8 + e;
      float c = cs[spos * 64 + d], si = sn[spos * 64 + d];
      float o = lo ? (xn[e] * c - pn[e] * si) : fmaf(xn[e], c, pn[e] * si);
      Kl[row][d] = f2bf(o);
    }
    u16x8 vv = *(const u16x8*)(qkv + (size_t)(b * SEQ_ + spos) * LDQKV + 2560 + g * 64 + ch * 8);
    #pragma unroll
    for (int e = 0; e < 8; ++e) Vl[row][ch * 8 + e] = vv[e];
  }
  __syncthreads();
  {
    int c = tid >> 5, row = tid & 31;
    u16x8 o;
    #pragma unroll
    for (int e = 0; e < 8; ++e) o[e] = Kl[row][c * 8 + e];
    *(u16x8*)(Kt + (((size_t)(bg * 64 + kt)) << 11) + (c * 32 + row) * 8) = o;
  }
  {
    int c = tid >> 6, d = tid & 63;
    u16x8 o;
    #pragma unroll
    for (int e = 0; e < 8; ++e) o[e] = Vl[c * 8 + e][d];
    *(u16x8*)(Vt + (((size_t)(bg * 64 + kt)) << 11) + (c * 64 + d) * 8) = o;
  }
}

// ---------- MFMA flash attention v14: counted-vmcnt 4-buffer ring ----------
// v11 task map (1024 blocks, 4 waves = 4 heads, balanced qt quadruple) +
// inline Q rms/rope. Key change: the k-loop no longer uses __syncthreads
// (which drains vmcnt to 0 and kills the prefetch). 4-buffer LDS ring
// (4 x 8KB = 32KB): per iter {wait vmcnt(2) -> buffer t ready, t+1 in
// flight; raw s_barrier; issue stage(t+2); body(t)}. Prefetch latency now
// hides under the body instead of being drained every iteration.
__global__ __launch_bounds__(256)
void attn_mfma14(const unsigned short* __restrict__ qkv, const float* __restrict__ qsc,
                 const unsigned short* __restrict__ Ktg, const unsigned short* __restrict__ Vtg,
                 unsigned short* __restrict__ ctx) {
  __shared__ __align__(16) unsigned short LR[16 * 1024];   // 4 bufs x (4KB K | 4KB V)
  const int tid = threadIdx.x;
  const int w = tid >> 6, lane = tid & 63;
  const int l31 = lane & 31, half = lane >> 5;
  const int bid = blockIdx.x;
  const int x8 = bid & 7, r = bid >> 3;
  const int bg = x8 + 8 * (r & 1);               // XCD-pinned (b,g)
  const int rr = r >> 1;
  const int slot = rr >> 4, gi = rr & 15;
  const int qt = (slot == 0) ? (63 - gi) : (slot == 1) ? gi
               : (slot == 2) ? (47 - gi) : (16 + gi);
  const int b = bg >> 3, g = bg & 7, h = g * 4 + w;
  const int qbase = qt * 32;
  const int nkt = qt + 1;

  // ---- inline Q RMSNorm + RoPE (computed sincos) + SM_C scale ----
  s16x8 qf[4];
  {
    const int spos = qbase + l31;
    float qv[4][8]; float sq = 0.f;
    #pragma unroll
    for (int s2 = 0; s2 < 4; ++s2) {
      u16x8 raw = *(const u16x8*)(qkv + (size_t)(b * SEQ_ + spos) * LDQKV + h * 64 + half * 8 + s2 * 16);
      #pragma unroll
      for (int e = 0; e < 8; ++e) { qv[s2][e] = bf2f(raw[e]); sq += qv[s2][e] * qv[s2][e]; }
    }
    sq += __shfl_xor(sq, 32);
    const float rn = rsqrtf(sq * (1.f / 64.f) + 1e-6f);
    float xn[4][8];
    #pragma unroll
    for (int s2 = 0; s2 < 4; ++s2)
      #pragma unroll
      for (int e = 0; e < 8; ++e) xn[s2][e] = qv[s2][e] * rn * qsc[s2 * 16 + half * 8 + e];
    const float fs = (float)spos;
    float qo[4][8];
    #pragma unroll
    for (int s2 = 0; s2 < 2; ++s2)
      #pragma unroll
      for (int e = 0; e < 8; ++e) {
        int d = s2 * 16 + half * 8 + e;
        float invf = exp2f((float)d * -0.4152410119f);  // 10000^(-d/32)
        float c0, s0;
        hw_sincos(fs * invf, c0, s0);
        qo[s2][e]     = (xn[s2][e] * c0 - xn[s2 + 2][e] * s0) * SM_C;
        qo[s2 + 2][e] = fmaf(xn[s2 + 2][e], c0, xn[s2][e] * s0) * SM_C;
      }
    #pragma unroll
    for (int s2 = 0; s2 < 4; ++s2) {
      u32x4 t;
      t[0] = pack_bf2(qo[s2][0], qo[s2][1]); t[1] = pack_bf2(qo[s2][2], qo[s2][3]);
      t[2] = pack_bf2(qo[s2][4], qo[s2][5]); t[3] = pack_bf2(qo[s2][6], qo[s2][7]);
      qf[s2] = __builtin_bit_cast(s16x8, t);
    }
  }

  f32x16 acc0 = {}, acc1 = {};
  float l_st = 0.f;

  const size_t tbase = ((size_t)(bg * 64)) << 11;
  const int soff = (w << 9) + lane * 8;          // u16 offset within a 4KB tile

  auto stage = [&](int kt_) {                    // issues 2 glds per wave (or 0)
    if (kt_ < nkt) {
      char* dst = (char*)LR + (kt_ & 3) * 8192;
      glds16(Ktg + tbase + ((size_t)kt_ << 11) + soff, dst + (w << 10));
      glds16(Vtg + tbase + ((size_t)kt_ << 11) + soff, dst + 4096 + (w << 10));
    }
  };

  auto body = [&](int kt_) {
    const char* Kb = (const char*)LR + (kt_ & 3) * 8192;
    const char* Vb = Kb + 4096;
    s16x8 KF0 = *(const s16x8*)(Kb + (((0 + half) << 5) + l31) * 16);
    s16x8 KF1 = *(const s16x8*)(Kb + (((2 + half) << 5) + l31) * 16);
    s16x8 KF2 = *(const s16x8*)(Kb + (((4 + half) << 5) + l31) * 16);
    s16x8 KF3 = *(const s16x8*)(Kb + (((6 + half) << 5) + l31) * 16);
    s16x8 vf00 = *(const s16x8*)(Vb + (((half) << 6) + l31) * 16);
    s16x8 vf01 = *(const s16x8*)(Vb + (((2 + half) << 6) + l31) * 16);
    s16x8 vf10 = *(const s16x8*)(Vb + (((half) << 6) + 32 + l31) * 16);
    s16x8 vf11 = *(const s16x8*)(Vb + (((2 + half) << 6) + 32 + l31) * 16);
    f32x16 st = {};
    __builtin_amdgcn_s_setprio(1);
    st = __builtin_amdgcn_mfma_f32_32x32x16_bf16(KF0, qf[0], st, 0, 0, 0);
    st = __builtin_amdgcn_mfma_f32_32x32x16_bf16(KF1, qf[1], st, 0, 0, 0);
    st = __builtin_amdgcn_mfma_f32_32x32x16_bf16(KF2, qf[2], st, 0, 0, 0);
    st = __builtin_amdgcn_mfma_f32_32x32x16_bf16(KF3, qf[3], st, 0, 0, 0);
    __builtin_amdgcn_s_setprio(0);
    if (kt_ == qt) {
      #pragma unroll
      for (int r2 = 0; r2 < 16; ++r2) {
        int key = (r2 & 3) + 8 * (r2 >> 2) + 4 * half;
        if (key > l31) st[r2] = ninf();
      }
    }
    float p[16];
    #pragma unroll
    for (int r2 = 0; r2 < 16; ++r2) p[r2] = exp2f(st[r2]);
    float s8[8];
    #pragma unroll
    for (int r2 = 0; r2 < 8; ++r2) s8[r2] = p[r2] + p[r2 + 8];
    float psum = ((s8[0] + s8[1]) + (s8[2] + s8[3])) + ((s8[4] + s8[5]) + (s8[6] + s8[7]));
    { float a2 = psum, b2 = psum; plswapf(a2, b2); psum = a2 + b2; }
    l_st += psum;
    unsigned int PK[8];
    #pragma unroll
    for (int j2 = 0; j2 < 8; ++j2) PK[j2] = pack_bf2(p[2 * j2], p[2 * j2 + 1]);
    plswap(PK[0], PK[2]); plswap(PK[1], PK[3]);
    plswap(PK[4], PK[6]); plswap(PK[5], PK[7]);
    u32x4 pb0u, pb1u;
    pb0u[0] = PK[0]; pb0u[1] = PK[1]; pb0u[2] = PK[2]; pb0u[3] = PK[3];
    pb1u[0] = PK[4]; pb1u[1] = PK[5]; pb1u[2] = PK[6]; pb1u[3] = PK[7];
    s16x8 pb0 = __builtin_bit_cast(s16x8, pb0u);
    s16x8 pb1 = __builtin_bit_cast(s16x8, pb1u);
    __builtin_amdgcn_s_setprio(1);
    acc0 = __builtin_amdgcn_mfma_f32_32x32x16_bf16(vf00, pb0, acc0, 0, 0, 0);
    acc1 = __builtin_amdgcn_mfma_f32_32x32x16_bf16(vf10, pb0, acc1, 0, 0, 0);
    acc0 = __builtin_amdgcn_mfma_f32_32x32x16_bf16(vf01, pb1, acc0, 0, 0, 0);
    acc1 = __builtin_amdgcn_mfma_f32_32x32x16_bf16(vf11, pb1, acc1, 0, 0, 0);
    __builtin_amdgcn_s_setprio(0);
  };

  stage(0);
  stage(1);
  for (int t = 0; t < nkt; ++t) {
    if (t + 1 < nkt) asm volatile("s_waitcnt vmcnt(2)" ::: "memory");
    else             asm volatile("s_waitcnt vmcnt(0)" ::: "memory");
    __builtin_amdgcn_sched_barrier(0);
    __builtin_amdgcn_s_barrier();
    __builtin_amdgcn_sched_barrier(0);
    stage(t + 2);                    // buffer (t+2)&3: last read at body(t-2), 2 barriers ago
    body(t);
  }

  const float linv = 1.f / l_st;
  unsigned short* orow = ctx + (size_t)(b * SEQ_ + qbase + l31) * 2048 + h * 64;
  #pragma unroll
  for (int dt = 0; dt < 2; ++dt) {
    #pragma unroll
    for (int rq = 0; rq < 4; ++rq) {
      const int rr2 = rq * 4;
      const int d0 = dt * 32 + 8 * rq + 4 * half;
      float a0 = (dt ? acc1[rr2]     : acc0[rr2])     * linv;
      float a1 = (dt ? acc1[rr2 + 1] : acc0[rr2 + 1]) * linv;
      float a2 = (dt ? acc1[rr2 + 2] : acc0[rr2 + 2]) * linv;
      float a3 = (dt ? acc1[rr2 + 3] : acc0[rr2 + 3]) * linv;
      u32x2 o;
      o[0] = pack_bf2(a0, a1);
      o[1] = pack_bf2(a2, a3);
      *(u32x2*)(orow + d0) = o;
    }
  }
}

extern "C" void kernel_launch(void* const* d_in, const int* in_sizes, int n_in,
                              void* d_out, int out_size, void* d_ws, size_t ws_size,
                              hipStream_t stream) {
  const float* x  = (const float*)d_in[0];
  const float* cs = (const float*)d_in[2];
  const float* sn = (const float*)d_in[3];
  const float* Wq = (const float*)d_in[4];
  const float* Wk = (const float*)d_in[5];
  const float* Wv = (const float*)d_in[6];
  const float* Wo = (const float*)d_in[7];
  const float* qs = (const float*)d_in[8];
  const float* ks = (const float*)d_in[9];
  float* out = (float*)d_out;

  unsigned short* xb  = (unsigned short*)d_ws;
  unsigned short* Wt  = xb  + (size_t)4096 * 2048;
  unsigned short* Wot = Wt  + (size_t)3072 * 2048;
  unsigned short* qkv = Wot + (size_t)2048 * 2048;
  unsigned short* vTb = qkv + (size_t)4096 * 3072;     // Vt tiles (4 MiB)
  unsigned short* ctx = vTb + (size_t)16 * 64 * 2048;
  unsigned short* Ktt = xb;                            // xb dead after QKV GEMM: Kt tiles

  prep<<<6656, 256, 0, stream>>>(x, Wq, Wk, Wv, Wo, xb, Wt, Wot);
  gemm256<256, 0><<<dim3(12, 16), 512, 0, stream>>>(xb, Wt, qkv, 3072);
  kvtile_rms<<<dim3(64, 16), 256, 0, stream>>>(qkv, ks, cs, sn, Ktt, vTb);
  attn_mfma14<<<1024, 256, 0, stream>>>(qkv, qs, Ktt, vTb, ctx);
  gemm256<128, 1><<<dim3(16, 16), 512, 0, stream>>>(ctx, Wot, out, 2048);
}

// Round 19
// 181.004 us; speedup vs baseline: 1.0599x; 1.0309x over previous
//
#include <hip/hip_runtime.h>
#include <hip/hip_bf16.h>
#include <cstdint>
#include <cstddef>

#define EMB   2048
#define NH_   32
#define NG_   8
#define DH_   64
#define SEQ_  2048
#define BB_   2
#define MTOT  4096
#define LDQKV 3072
#define SM_C  0.18033688f   // 0.125 * log2(e)

typedef __attribute__((ext_vector_type(8))) short s16x8;
typedef __attribute__((ext_vector_type(8))) unsigned short u16x8;
typedef __attribute__((ext_vector_type(4))) float f32x4;
typedef __attribute__((ext_vector_type(16))) float f32x16;
typedef __attribute__((ext_vector_type(4))) unsigned int u32x4;
typedef __attribute__((ext_vector_type(2))) unsigned int u32x2;
typedef __attribute__((ext_vector_type(2))) int i32x2;

__device__ __forceinline__ float bf2f(unsigned short u) {
  unsigned int x = (unsigned int)u << 16; return __uint_as_float(x);
}
__device__ __forceinline__ unsigned short f2bf(float f) {
  unsigned int x = __float_as_uint(f);
  x = x + 0x7FFFu + ((x >> 16) & 1u);          // RNE
  return (unsigned short)(x >> 16);
}
__device__ __forceinline__ float ninf() { return __int_as_float(0xff800000); }
__device__ __forceinline__ unsigned int pack_bf2(float a, float b) {
  unsigned int r;
  asm("v_cvt_pk_bf16_f32 %0, %1, %2" : "=v"(r) : "v"(a), "v"(b));
  return r;
}
// lane i (<32): a.lo stays, a.hi <- b.lo ; b.lo <- a.hi, b.hi stays (32-lane half swap)
__device__ __forceinline__ void plswap(unsigned int& a, unsigned int& b) {
  i32x2 r = __builtin_amdgcn_permlane32_swap((int)a, (int)b, false, false);
  a = (unsigned int)r[0]; b = (unsigned int)r[1];
}
__device__ __forceinline__ void plswapf(float& a, float& b) {
  unsigned int ua = __float_as_uint(a), ub = __float_as_uint(b);
  plswap(ua, ub);
  a = __uint_as_float(ua); b = __uint_as_float(ub);
}

__device__ __forceinline__ void glds16(const void* g, void* l) {
  __builtin_amdgcn_global_load_lds((const __attribute__((address_space(1))) void*)g,
                                   (__attribute__((address_space(3))) void*)l, 16, 0, 0);
}

// hw sincos, input radians; revolutions conversion + range reduction
__device__ __forceinline__ void hw_sincos(float ang, float& c, float& s) {
  float rev = ang * 0.15915494309f;
  rev = rev - floorf(rev);
  asm("v_cos_f32 %0, %1" : "=v"(c) : "v"(rev));
  asm("v_sin_f32 %0, %1" : "=v"(s) : "v"(rev));
}

// ---------- merged prep: x f32->bf16 (seg 0) + 4 weight transposes (segs 1..4) ----------
__global__ __launch_bounds__(256)
void prep(const float* __restrict__ x, const float* __restrict__ Wq,
          const float* __restrict__ Wk, const float* __restrict__ Wv,
          const float* __restrict__ Wo, unsigned short* __restrict__ xb,
          unsigned short* __restrict__ Wt, unsigned short* __restrict__ Wot) {
  __shared__ float tile[64][65];
  const int tid = threadIdx.x;
  const int bid = blockIdx.x;
  if (bid < 4096) {                       // cvtx
    size_t i = (size_t)bid * 256 + tid;
    float4 a = *(const float4*)(x + i * 8);
    float4 c = *(const float4*)(x + i * 8 + 4);
    u16x8 o;
    o[0] = f2bf(a.x); o[1] = f2bf(a.y); o[2] = f2bf(a.z); o[3] = f2bf(a.w);
    o[4] = f2bf(c.x); o[5] = f2bf(c.y); o[6] = f2bf(c.z); o[7] = f2bf(c.w);
    *(u16x8*)(xb + i * 8) = o;
    return;
  }
  const float* in; unsigned short* out; int N; int local;
  if (bid < 5120)      { in = Wq; out = Wt;                       N = 2048; local = bid - 4096; }
  else if (bid < 5376) { in = Wk; out = Wt + (size_t)2048 * 2048; N = 512;  local = bid - 5120; }
  else if (bid < 5632) { in = Wv; out = Wt + (size_t)2560 * 2048; N = 512;  local = bid - 5376; }
  else                 { in = Wo; out = Wot;                      N = 2048; local = bid - 5632; }
  const int ntile = N >> 6;
  const int n0 = (local % ntile) * 64, k0 = (local / ntile) * 64;
  #pragma unroll
  for (int jj = 0; jj < 4; ++jj) {
    int r = (tid >> 4) + jj * 16;
    int c = (tid & 15) * 4;
    float4 v = *(const float4*)(in + (size_t)(k0 + r) * N + n0 + c);
    tile[r][c] = v.x; tile[r][c + 1] = v.y; tile[r][c + 2] = v.z; tile[r][c + 3] = v.w;
  }
  __syncthreads();
  #pragma unroll
  for (int rep = 0; rep < 2; ++rep) {
    int u = rep * 256 + tid;
    int nl = u >> 3, ch = u & 7;
    u16x8 o;
    #pragma unroll
    for (int e = 0; e < 8; ++e) o[e] = f2bf(tile[ch * 8 + e][nl]);
    *(u16x8*)(out + (size_t)(n0 + nl) * 2048 + k0 + ch * 8) = o;
  }
}

// ---------- counted-vmcnt 256xBN GEMM: C = A[M,2048] @ Bt[N,2048]^T ----------
// Swizzle (both-sides involution): 16B-chunk ^= (row>>1)&3 -> 2-way banks (free).
template<int BN, int F32OUT>
__global__ __launch_bounds__(512, 1)
void gemm256(const unsigned short* __restrict__ A, const unsigned short* __restrict__ Bt,
             void* __restrict__ C, int ldc) {
  constexpr int BUF = 16384 + BN * 64;
  constexpr int WN = BN / 64;
  constexpr int RW = 256 / (8 / WN);
  __shared__ __align__(16) char L[4][BUF];
  const int tid = threadIdx.x;
  const int wid = tid >> 6, lane = tid & 63;
  const int wm = wid / WN, wn = wid % WN;
  const int grp = lane >> 4, l15 = lane & 15;
  const int bm = blockIdx.y * 256, bn = blockIdx.x * BN;
  const int nt = 64;

  const int srow = tid >> 2;
  const int sc = (tid & 3) ^ ((srow >> 1) & 3);  // pre-swizzled source chunk
  const int grp2 = grp ^ ((l15 >> 1) & 3);       // swizzled ds_read chunk

  auto stage_ht = [&](int t, int h) {
    const unsigned short* src = (h < 2)
      ? A  + (size_t)(bm + h * 128 + srow) * 2048 + t * 32 + sc * 8
      : Bt + (size_t)(bn + (h - 2) * 128 + srow) * 2048 + t * 32 + sc * 8;
    glds16(src, &L[t & 3][h * 8192 + wid * 1024]);
  };

  constexpr int NST = 2 + BN / 128;
  f32x4 acc[RW / 16][4] = {};

  #pragma unroll
  for (int h = 0; h < NST; ++h) stage_ht(0, h);
  #pragma unroll
  for (int h = 0; h < NST; ++h) stage_ht(1, h);
  if constexpr (BN == 256) asm volatile("s_waitcnt vmcnt(4)" ::: "memory");
  else                     asm volatile("s_waitcnt vmcnt(3)" ::: "memory");
  __builtin_amdgcn_sched_barrier(0);
  __builtin_amdgcn_s_barrier();
  __builtin_amdgcn_sched_barrier(0);

  for (int t = 0; t < nt; ++t) {
    const char* Ab = &L[t & 3][0]     + (size_t)(wm * RW + l15) * 64 + grp2 * 16;
    const char* Bb = &L[t & 3][16384] + (size_t)(wn * 64 + l15) * 64 + grp2 * 16;
    const bool pre = (t + 2 < nt);
    if (pre) { stage_ht(t + 2, 0); stage_ht(t + 2, 1); }
    s16x8 bf[4], af[4];
    #pragma unroll
    for (int j = 0; j < 4; ++j) bf[j] = *(const s16x8*)(Bb + j * 1024);
    #pragma unroll
    for (int i = 0; i < 4; ++i) af[i] = *(const s16x8*)(Ab + i * 1024);
    __builtin_amdgcn_s_setprio(1);
    #pragma unroll
    for (int i = 0; i < 4; ++i)
      #pragma unroll
      for (int j = 0; j < 4; ++j)
        acc[i][j] = __builtin_amdgcn_mfma_f32_16x16x32_bf16(af[i], bf[j], acc[i][j], 0, 0, 0);
    __builtin_amdgcn_s_setprio(0);
    if constexpr (BN == 256) {
      if (pre) { stage_ht(t + 2, 2); stage_ht(t + 2, 3); }
      #pragma unroll
      for (int i = 0; i < 4; ++i) af[i] = *(const s16x8*)(Ab + (4 + i) * 1024);
      __builtin_amdgcn_s_setprio(1);
      #pragma unroll
      for (int i = 0; i < 4; ++i)
        #pragma unroll
        for (int j = 0; j < 4; ++j)
          acc[4 + i][j] = __builtin_amdgcn_mfma_f32_16x16x32_bf16(af[i], bf[j], acc[4 + i][j], 0, 0, 0);
      __builtin_amdgcn_s_setprio(0);
    } else {
      if (pre) stage_ht(t + 2, 2);
    }
    if (t + 1 < nt) {
      if (pre) {
        if constexpr (BN == 256) asm volatile("s_waitcnt vmcnt(4)" ::: "memory");
        else                     asm volatile("s_waitcnt vmcnt(3)" ::: "memory");
      } else {
        asm volatile("s_waitcnt vmcnt(0)" ::: "memory");
      }
      __builtin_amdgcn_sched_barrier(0);
      __builtin_amdgcn_s_barrier();
      __builtin_amdgcn_sched_barrier(0);
    }
  }

  #pragma unroll
  for (int i = 0; i < RW / 16; ++i)
    #pragma unroll
    for (int j = 0; j < 4; ++j)
      #pragma unroll
      for (int r = 0; r < 4; ++r) {
        int row = bm + wm * RW + i * 16 + grp * 4 + r;
        int col = bn + wn * 64 + j * 16 + l15;
        float v = acc[i][j][r];
        if (F32OUT) ((float*)C)[(size_t)row * ldc + col] = v;
        else        ((unsigned short*)C)[(size_t)row * ldc + col] = f2bf(v);
      }
}

// ---------- K/V pre-tiling + fused K RMSNorm/RoPE ----------
__global__ __launch_bounds__(256)
void kvtile_rms(const unsigned short* __restrict__ qkv, const float* __restrict__ ksc,
                const float* __restrict__ cs, const float* __restrict__ sn,
                unsigned short* __restrict__ Kt, unsigned short* __restrict__ Vt) {
  __shared__ unsigned short Kl[32][72];
  __shared__ unsigned short Vl[32][72];
  const int tid = threadIdx.x;
  const int kt = blockIdx.x;
  const int bg = blockIdx.y;
  const int b = bg >> 3, g = bg & 7;
  {
    const int row = tid >> 3, ch = tid & 7;
    const int spos = kt * 32 + row;
    u16x8 kv = *(const u16x8*)(qkv + (size_t)(b * SEQ_ + spos) * LDQKV + 2048 + g * 64 + ch * 8);
    float v[8]; float sq = 0.f;
    #pragma unroll
    for (int e = 0; e < 8; ++e) { v[e] = bf2f(kv[e]); sq += v[e] * v[e]; }
    sq += __shfl_xor(sq, 1); sq += __shfl_xor(sq, 2); sq += __shfl_xor(sq, 4);
    const float rn = rsqrtf(sq * (1.f / 64.f) + 1e-6f);
    float xn[8];
    #pragma unroll
    for (int e = 0; e < 8; ++e) xn[e] = v[e] * rn * ksc[ch * 8 + e];
    float pn[8];
    #pragma unroll
    for (int e = 0; e < 8; ++e) pn[e] = __shfl_xor(xn[e], 4);
    const bool lo = (ch < 4);
    #pragma unroll
    for (int e = 0; e < 8; ++e) {
      int d = ch * 8 + e;
      float c = cs[spos * 64 + d], si = sn[spos * 64 + d];
      float o = lo ? (xn[e] * c - pn[e] * si) : fmaf(xn[e], c, pn[e] * si);
      Kl[row][d] = f2bf(o);
    }
    u16x8 vv = *(const u16x8*)(qkv + (size_t)(b * SEQ_ + spos) * LDQKV + 2560 + g * 64 + ch * 8);
    #pragma unroll
    for (int e = 0; e < 8; ++e) Vl[row][ch * 8 + e] = vv[e];
  }
  __syncthreads();
  {
    int c = tid >> 5, row = tid & 31;
    u16x8 o;
    #pragma unroll
    for (int e = 0; e < 8; ++e) o[e] = Kl[row][c * 8 + e];
    *(u16x8*)(Kt + (((size_t)(bg * 64 + kt)) << 11) + (c * 32 + row) * 8) = o;
  }
  {
    int c = tid >> 6, d = tid & 63;
    u16x8 o;
    #pragma unroll
    for (int e = 0; e < 8; ++e) o[e] = Vl[c * 8 + e][d];
    *(u16x8*)(Vt + (((size_t)(bg * 64 + kt)) << 11) + (c * 64 + d) * 8) = o;
  }
}

// ---------- MFMA flash attention v11 (measured best: 69.3 us) ----------
// 1024 blocks, 4 waves = 4 heads per (b,g); balanced qt quadruple; KVBLK=64
// double-buffered LDS (LA/LB); inline Q rms/rope with computed sincos;
// no-max softmax (exact: RMSNorm bounds logits); cvt_pk + permlane32_swap.
__global__ __launch_bounds__(256)
void attn_mfma11(const unsigned short* __restrict__ qkv, const float* __restrict__ qsc,
                 const unsigned short* __restrict__ Ktg, const unsigned short* __restrict__ Vtg,
                 unsigned short* __restrict__ ctx) {
  __shared__ __align__(16) unsigned short LA[8 * 1024];
  __shared__ __align__(16) unsigned short LB[8 * 1024];
  const int tid = threadIdx.x;
  const int w = tid >> 6, lane = tid & 63;
  const int l31 = lane & 31, half = lane >> 5;
  const int bid = blockIdx.x;
  const int x8 = bid & 7, r = bid >> 3;
  const int bg = x8 + 8 * (r & 1);
  const int rr = r >> 1;
  const int slot = rr >> 4, gi = rr & 15;
  const int qt = (slot == 0) ? (63 - gi) : (slot == 1) ? gi
               : (slot == 2) ? (47 - gi) : (16 + gi);
  const int b = bg >> 3, g = bg & 7, h = g * 4 + w;
  const int qbase = qt * 32;
  const int nkt = qt + 1;
  const int nit = (nkt + 1) >> 1;

  // ---- inline Q RMSNorm + RoPE (computed sincos) + SM_C scale ----
  s16x8 qf[4];
  {
    const int spos = qbase + l31;
    float qv[4][8]; float sq = 0.f;
    #pragma unroll
    for (int s2 = 0; s2 < 4; ++s2) {
      u16x8 raw = *(const u16x8*)(qkv + (size_t)(b * SEQ_ + spos) * LDQKV + h * 64 + half * 8 + s2 * 16);
      #pragma unroll
      for (int e = 0; e < 8; ++e) { qv[s2][e] = bf2f(raw[e]); sq += qv[s2][e] * qv[s2][e]; }
    }
    sq += __shfl_xor(sq, 32);
    const float rn = rsqrtf(sq * (1.f / 64.f) + 1e-6f);
    float xn[4][8];
    #pragma unroll
    for (int s2 = 0; s2 < 4; ++s2)
      #pragma unroll
      for (int e = 0; e < 8; ++e) xn[s2][e] = qv[s2][e] * rn * qsc[s2 * 16 + half * 8 + e];
    const float fs = (float)spos;
    float qo[4][8];
    #pragma unroll
    for (int s2 = 0; s2 < 2; ++s2)
      #pragma unroll
      for (int e = 0; e < 8; ++e) {
        int d = s2 * 16 + half * 8 + e;                  // d < 32; cos[d] == cos[d+32]
        float invf = exp2f((float)d * -0.4152410119f);   // 10000^(-d/32)
        float c0, s0;
        hw_sincos(fs * invf, c0, s0);
        qo[s2][e]     = (xn[s2][e] * c0 - xn[s2 + 2][e] * s0) * SM_C;
        qo[s2 + 2][e] = fmaf(xn[s2 + 2][e], c0, xn[s2][e] * s0) * SM_C;
      }
    #pragma unroll
    for (int s2 = 0; s2 < 4; ++s2) {
      u32x4 t;
      t[0] = pack_bf2(qo[s2][0], qo[s2][1]); t[1] = pack_bf2(qo[s2][2], qo[s2][3]);
      t[2] = pack_bf2(qo[s2][4], qo[s2][5]); t[3] = pack_bf2(qo[s2][6], qo[s2][7]);
      qf[s2] = __builtin_bit_cast(s16x8, t);
    }
  }

  f32x16 acc0 = {}, acc1 = {};
  float l_st = 0.f;

  const size_t tbase = ((size_t)(bg * 64)) << 11;
  const int soff = (w << 9) + lane * 8;

  auto stage = [&](unsigned short* Lb, int pi) {
    const int kt0 = 2 * pi, kt1 = 2 * pi + 1;
    glds16(Ktg + tbase + ((size_t)kt0 << 11) + soff, (char*)Lb + (w << 10));
    glds16(Vtg + tbase + ((size_t)kt0 << 11) + soff, (char*)Lb + 8192 + (w << 10));
    if (kt1 < nkt) {
      glds16(Ktg + tbase + ((size_t)kt1 << 11) + soff, (char*)Lb + 4096 + (w << 10));
      glds16(Vtg + tbase + ((size_t)kt1 << 11) + soff, (char*)Lb + 12288 + (w << 10));
    }
  };

  auto sub = [&](const char* Kb, const char* Vb, bool diag, float& lsum) {
    s16x8 KF0 = *(const s16x8*)(Kb + (((0 + half) << 5) + l31) * 16);
    s16x8 KF1 = *(const s16x8*)(Kb + (((2 + half) << 5) + l31) * 16);
    s16x8 KF2 = *(const s16x8*)(Kb + (((4 + half) << 5) + l31) * 16);
    s16x8 KF3 = *(const s16x8*)(Kb + (((6 + half) << 5) + l31) * 16);
    s16x8 vf00 = *(const s16x8*)(Vb + (((half) << 6) + l31) * 16);
    s16x8 vf01 = *(const s16x8*)(Vb + (((2 + half) << 6) + l31) * 16);
    s16x8 vf10 = *(const s16x8*)(Vb + (((half) << 6) + 32 + l31) * 16);
    s16x8 vf11 = *(const s16x8*)(Vb + (((2 + half) << 6) + 32 + l31) * 16);
    f32x16 st = {};
    __builtin_amdgcn_s_setprio(1);
    st = __builtin_amdgcn_mfma_f32_32x32x16_bf16(KF0, qf[0], st, 0, 0, 0);
    st = __builtin_amdgcn_mfma_f32_32x32x16_bf16(KF1, qf[1], st, 0, 0, 0);
    st = __builtin_amdgcn_mfma_f32_32x32x16_bf16(KF2, qf[2], st, 0, 0, 0);
    st = __builtin_amdgcn_mfma_f32_32x32x16_bf16(KF3, qf[3], st, 0, 0, 0);
    __builtin_amdgcn_s_setprio(0);
    if (diag) {
      #pragma unroll
      for (int r2 = 0; r2 < 16; ++r2) {
        int key = (r2 & 3) + 8 * (r2 >> 2) + 4 * half;
        if (key > l31) st[r2] = ninf();
      }
    }
    float p[16];
    #pragma unroll
    for (int r2 = 0; r2 < 16; ++r2) p[r2] = exp2f(st[r2]);
    float s8[8];
    #pragma unroll
    for (int r2 = 0; r2 < 8; ++r2) s8[r2] = p[r2] + p[r2 + 8];
    lsum += ((s8[0] + s8[1]) + (s8[2] + s8[3])) + ((s8[4] + s8[5]) + (s8[6] + s8[7]));
    unsigned int PK[8];
    #pragma unroll
    for (int j2 = 0; j2 < 8; ++j2) PK[j2] = pack_bf2(p[2 * j2], p[2 * j2 + 1]);
    plswap(PK[0], PK[2]); plswap(PK[1], PK[3]);
    plswap(PK[4], PK[6]); plswap(PK[5], PK[7]);
    u32x4 pb0u, pb1u;
    pb0u[0] = PK[0]; pb0u[1] = PK[1]; pb0u[2] = PK[2]; pb0u[3] = PK[3];
    pb1u[0] = PK[4]; pb1u[1] = PK[5]; pb1u[2] = PK[6]; pb1u[3] = PK[7];
    s16x8 pb0 = __builtin_bit_cast(s16x8, pb0u);
    s16x8 pb1 = __builtin_bit_cast(s16x8, pb1u);
    __builtin_amdgcn_s_setprio(1);
    acc0 = __builtin_amdgcn_mfma_f32_32x32x16_bf16(vf00, pb0, acc0, 0, 0, 0);
    acc1 = __builtin_amdgcn_mfma_f32_32x32x16_bf16(vf10, pb0, acc1, 0, 0, 0);
    acc0 = __builtin_amdgcn_mfma_f32_32x32x16_bf16(vf01, pb1, acc0, 0, 0, 0);
    acc1 = __builtin_amdgcn_mfma_f32_32x32x16_bf16(vf11, pb1, acc1, 0, 0, 0);
    __builtin_amdgcn_s_setprio(0);
  };

  auto pair_body = [&](const unsigned short* Lb, int pi) {
    const int kt0 = 2 * pi, kt1 = 2 * pi + 1;
    float lsum = 0.f;
    sub((const char*)Lb, (const char*)Lb + 8192, kt0 == qt, lsum);
    if (kt1 < nkt)
      sub((const char*)Lb + 4096, (const char*)Lb + 12288, kt1 == qt, lsum);
    { float a2 = lsum, b2 = lsum; plswapf(a2, b2); lsum = a2 + b2; }
    l_st += lsum;
  };

  stage(LA, 0);
  int pi = 0;
  while (true) {
    __syncthreads();
    if (pi + 1 < nit) stage(LB, pi + 1);
    pair_body(LA, pi);
    ++pi; if (pi >= nit) break;
    __syncthreads();
    if (pi + 1 < nit) stage(LA, pi + 1);
    pair_body(LB, pi);
    ++pi; if (pi >= nit) break;
  }

  const float linv = 1.f / l_st;
  unsigned short* orow = ctx + (size_t)(b * SEQ_ + qbase + l31) * 2048 + h * 64;
  #pragma unroll
  for (int dt = 0; dt < 2; ++dt) {
    #pragma unroll
    for (int rq = 0; rq < 4; ++rq) {
      const int rr2 = rq * 4;
      const int d0 = dt * 32 + 8 * rq + 4 * half;
      float a0 = (dt ? acc1[rr2]     : acc0[rr2])     * linv;
      float a1 = (dt ? acc1[rr2 + 1] : acc0[rr2 + 1]) * linv;
      float a2 = (dt ? acc1[rr2 + 2] : acc0[rr2 + 2]) * linv;
      float a3 = (dt ? acc1[rr2 + 3] : acc0[rr2 + 3]) * linv;
      u32x2 o;
      o[0] = pack_bf2(a0, a1);
      o[1] = pack_bf2(a2, a3);
      *(u32x2*)(orow + d0) = o;
    }
  }
}

extern "C" void kernel_launch(void* const* d_in, const int* in_sizes, int n_in,
                              void* d_out, int out_size, void* d_ws, size_t ws_size,
                              hipStream_t stream) {
  const float* x  = (const float*)d_in[0];
  const float* cs = (const float*)d_in[2];
  const float* sn = (const float*)d_in[3];
  const float* Wq = (const float*)d_in[4];
  const float* Wk = (const float*)d_in[5];
  const float* Wv = (const float*)d_in[6];
  const float* Wo = (const float*)d_in[7];
  const float* qs = (const float*)d_in[8];
  const float* ks = (const float*)d_in[9];
  float* out = (float*)d_out;

  unsigned short* xb  = (unsigned short*)d_ws;
  unsigned short* Wt  = xb  + (size_t)4096 * 2048;
  unsigned short* Wot = Wt  + (size_t)3072 * 2048;
  unsigned short* qkv = Wot + (size_t)2048 * 2048;
  unsigned short* vTb = qkv + (size_t)4096 * 3072;     // Vt tiles (4 MiB)
  unsigned short* ctx = vTb + (size_t)16 * 64 * 2048;
  unsigned short* Ktt = xb;                            // xb dead after QKV GEMM: Kt tiles

  prep<<<6656, 256, 0, stream>>>(x, Wq, Wk, Wv, Wo, xb, Wt, Wot);
  gemm256<256, 0><<<dim3(12, 16), 512, 0, stream>>>(xb, Wt, qkv, 3072);
  kvtile_rms<<<dim3(64, 16), 256, 0, stream>>>(qkv, ks, cs, sn, Ktt, vTb);
  attn_mfma11<<<1024, 256, 0, stream>>>(qkv, qs, Ktt, vTb, ctx);
  gemm256<128, 1><<<dim3(16, 16), 512, 0, stream>>>(ctx, Wot, out, 2048);
}